// Round 1
// baseline (2574.178 us; speedup 1.0000x reference)
//
#include <hip/hip_runtime.h>
#include <hip/hip_bf16.h>
#include <math.h>

#define N_NODES 50000
#define E_EDGES 500000
#define EPRIME  (E_EDGES + N_NODES)
#define HID     256
#define PRE_IN  1024
#define OUT_DIM 64
#define NHEAD   4
#define DHEAD   64
#define LAYERS  2
#define NTYPES  2

// ---------------------------------------------------------------- GEMM f32
// C[M,N] = op( A[M,K] @ B[K,N] + bias + Cin ), 128x128 tile, 8x8/thread.
#define BM 128
#define BN 128
#define BK 16

__global__ __launch_bounds__(256) void gemm_f32(
    const float* __restrict__ A, int lda,
    const float* __restrict__ B, int ldb,
    float* __restrict__ C, int ldc,
    const float* __restrict__ Cin,   // accumulate source (read) or null
    const float* __restrict__ bias,  // [N] or null
    int M, int N, int K, int relu)
{
  __shared__ float As[BK][BM + 4];
  __shared__ float Bs[BK][BN + 4];
  const int bm = blockIdx.y * BM;
  const int bn = blockIdx.x * BN;
  const int tid = threadIdx.x;
  const int ty = tid >> 4;
  const int tx = tid & 15;
  float acc[8][8];
#pragma unroll
  for (int i = 0; i < 8; i++)
#pragma unroll
    for (int j = 0; j < 8; j++) acc[i][j] = 0.f;

  for (int k0 = 0; k0 < K; k0 += BK) {
    // A tile 128x16 -> LDS transposed
#pragma unroll
    for (int i = 0; i < 2; i++) {
      int f = tid + i * 256;
      int r = f >> 2;
      int cb = (f & 3) << 2;
      int gr = bm + r;
      float4 v = make_float4(0.f, 0.f, 0.f, 0.f);
      if (gr < M) v = *reinterpret_cast<const float4*>(A + (size_t)gr * lda + (k0 + cb));
      As[cb + 0][r] = v.x; As[cb + 1][r] = v.y; As[cb + 2][r] = v.z; As[cb + 3][r] = v.w;
    }
    // B tile 16x128
#pragma unroll
    for (int i = 0; i < 2; i++) {
      int f = tid + i * 256;
      int r = f >> 5;
      int c = (f & 31) << 2;
      int gc = bn + c;
      float4 v = make_float4(0.f, 0.f, 0.f, 0.f);
      if (gc < N) v = *reinterpret_cast<const float4*>(B + (size_t)(k0 + r) * ldb + gc);
      *reinterpret_cast<float4*>(&Bs[r][c]) = v;
    }
    __syncthreads();
#pragma unroll
    for (int kk = 0; kk < BK; kk++) {
      float a[8], b[8];
      *(float4*)&a[0] = *(const float4*)&As[kk][ty * 4];
      *(float4*)&a[4] = *(const float4*)&As[kk][64 + ty * 4];
      *(float4*)&b[0] = *(const float4*)&Bs[kk][tx * 4];
      *(float4*)&b[4] = *(const float4*)&Bs[kk][64 + tx * 4];
#pragma unroll
      for (int i = 0; i < 8; i++)
#pragma unroll
        for (int j = 0; j < 8; j++)
          acc[i][j] = fmaf(a[i], b[j], acc[i][j]);
    }
    __syncthreads();
  }
#pragma unroll
  for (int ih = 0; ih < 2; ih++) {
#pragma unroll
    for (int i = 0; i < 4; i++) {
      int gr = bm + ih * 64 + ty * 4 + i;
      if (gr < M) {
#pragma unroll
        for (int jh = 0; jh < 2; jh++) {
          int gc = bn + jh * 64 + tx * 4;
          if (gc < N) {
            float4 v;
            v.x = acc[ih * 4 + i][jh * 4 + 0];
            v.y = acc[ih * 4 + i][jh * 4 + 1];
            v.z = acc[ih * 4 + i][jh * 4 + 2];
            v.w = acc[ih * 4 + i][jh * 4 + 3];
            if (bias) {
              const float4 b4 = *reinterpret_cast<const float4*>(bias + gc);
              v.x += b4.x; v.y += b4.y; v.z += b4.z; v.w += b4.w;
            }
            if (Cin) {
              const float4 c4 = *reinterpret_cast<const float4*>(Cin + (size_t)gr * ldc + gc);
              v.x += c4.x; v.y += c4.y; v.z += c4.z; v.w += c4.w;
            }
            if (relu) {
              v.x = fmaxf(v.x, 0.f); v.y = fmaxf(v.y, 0.f);
              v.z = fmaxf(v.z, 0.f); v.w = fmaxf(v.w, 0.f);
            }
            *reinterpret_cast<float4*>(C + (size_t)gr * ldc + gc) = v;
          }
        }
      }
    }
  }
}

// ------------------------------------------------------------ LayerNorm+ReLU
// one wave per row of 256
__global__ void ln_relu(const float* __restrict__ in, float* __restrict__ out,
                        const float* __restrict__ g, const float* __restrict__ be, int n)
{
  int gid = blockIdx.x * blockDim.x + threadIdx.x;
  int row = gid >> 6;
  int lane = threadIdx.x & 63;
  if (row >= n) return;
  float4 v = *reinterpret_cast<const float4*>(in + (size_t)row * HID + lane * 4);
  float s = v.x + v.y + v.z + v.w;
  float ss = v.x * v.x + v.y * v.y + v.z * v.z + v.w * v.w;
#pragma unroll
  for (int o = 1; o < 64; o <<= 1) { s += __shfl_xor(s, o); ss += __shfl_xor(ss, o); }
  float mu = s * (1.f / 256.f);
  float var = ss * (1.f / 256.f) - mu * mu;
  float inv = rsqrtf(var + 1e-5f);
  float4 gg = *reinterpret_cast<const float4*>(g + lane * 4);
  float4 bb = *reinterpret_cast<const float4*>(be + lane * 4);
  float4 o4;
  o4.x = fmaxf((v.x - mu) * inv * gg.x + bb.x, 0.f);
  o4.y = fmaxf((v.y - mu) * inv * gg.y + bb.y, 0.f);
  o4.z = fmaxf((v.z - mu) * inv * gg.z + bb.z, 0.f);
  o4.w = fmaxf((v.w - mu) * inv * gg.w + bb.w, 0.f);
  *reinterpret_cast<float4*>(out + (size_t)row * HID + lane * 4) = o4;
}

// ------------------------------------------------------------- CSR building
__global__ void csr_count(const int* __restrict__ ei, int* __restrict__ count)
{
  int e = blockIdx.x * blockDim.x + threadIdx.x;
  if (e >= EPRIME) return;
  int d = (e < E_EDGES) ? ei[E_EDGES + e] : (e - E_EDGES);
  atomicAdd(&count[d], 1);
}

__global__ __launch_bounds__(1024) void csr_scan(
    int* __restrict__ c0, int* __restrict__ o0, int* __restrict__ u0,
    int* __restrict__ c1, int* __restrict__ o1, int* __restrict__ u1, int n)
{
  int* count = blockIdx.x ? c1 : c0;
  int* offs  = blockIdx.x ? o1 : o0;
  int* cur   = blockIdx.x ? u1 : u0;
  __shared__ int partial[1024];
  int tid = threadIdx.x;
  int chunk = (n + 1023) / 1024;
  int b = tid * chunk;
  int s = 0;
  for (int i = 0; i < chunk; i++) { int idx = b + i; if (idx < n) s += count[idx]; }
  partial[tid] = s;
  __syncthreads();
  for (int o = 1; o < 1024; o <<= 1) {
    int v = (tid >= o) ? partial[tid - o] : 0;
    __syncthreads();
    partial[tid] += v;
    __syncthreads();
  }
  int run = (tid == 0) ? 0 : partial[tid - 1];
  for (int i = 0; i < chunk; i++) {
    int idx = b + i;
    if (idx < n) { offs[idx] = run; cur[idx] = run; run += count[idx]; }
  }
  if (tid == 1023) offs[n] = partial[1023];
}

__global__ void csr_scatter(const int* __restrict__ ei, int* __restrict__ cur,
                            int* __restrict__ csr_src)
{
  int e = blockIdx.x * blockDim.x + threadIdx.x;
  if (e >= EPRIME) return;
  int d = (e < E_EDGES) ? ei[E_EDGES + e] : (e - E_EDGES);
  int s = (e < E_EDGES) ? ei[e] : (e - E_EDGES);
  int pos = atomicAdd(&cur[d], 1);
  csr_src[pos] = s;
}

// deterministic order (sorted by src id) regardless of scatter race order
__global__ void csr_sort(const int* __restrict__ offs, int* __restrict__ csr_src, int n)
{
  int d = blockIdx.x * blockDim.x + threadIdx.x;
  if (d >= n) return;
  int b = offs[d], e = offs[d + 1];
  for (int i = b + 1; i < e; i++) {
    int v = csr_src[i];
    int j = i - 1;
    while (j >= b && csr_src[j] > v) { csr_src[j + 1] = csr_src[j]; j--; }
    csr_src[j + 1] = v;
  }
}

// -------------------------------------------------- concat Wl|Wr per (l,t)
// Wcat[l][k][t*512 + half*256 + c] = (half?Wr:Wl)[l][t][k][c]
__global__ void concat_w(const float* __restrict__ Wl, const float* __restrict__ Wr,
                         float* __restrict__ Wcat)
{
  int i = blockIdx.x * blockDim.x + threadIdx.x;
  if (i >= LAYERS * 256 * 1024) return;
  int l = i >> 18;
  int rem = i & 262143;
  int k = rem >> 10;
  int c = rem & 1023;
  int t = c >> 9;
  int half = (c >> 8) & 1;
  int cc = c & 255;
  const float* W = half ? Wr : Wl;
  Wcat[i] = W[(((size_t)l * NTYPES + t) * 256 + k) * 256 + cc];
}

// ---------------------------------------------- GATv2: dst-centric online SM
// one wave per dst node; lane owns 4 channels (head = lane/16)
__global__ void gat_edge(const float* __restrict__ xlr,       // [N,1024]
                         const int* __restrict__ offs,        // [N+1]
                         const int* __restrict__ csr_src,     // [E']
                         const float* __restrict__ att,       // [256] for (l,t)
                         const float* __restrict__ bias,      // [256]
                         float* __restrict__ out,             // [N,256]
                         int n, int xl_col, int xr_col)
{
  int gid = blockIdx.x * blockDim.x + threadIdx.x;
  int wid = gid >> 6;
  int lane = threadIdx.x & 63;
  if (wid >= n) return;

  const float4 xr = *reinterpret_cast<const float4*>(xlr + (size_t)wid * 1024 + xr_col + lane * 4);
  const float4 av = *reinterpret_cast<const float4*>(att + lane * 4);
  int beg = offs[wid], end = offs[wid + 1];

  float m = -INFINITY, den = 0.f;
  float4 acc = make_float4(0.f, 0.f, 0.f, 0.f);

  for (int j = beg; j < end; j++) {
    int s = csr_src[j];
    float4 hs = *reinterpret_cast<const float4*>(xlr + (size_t)s * 1024 + xl_col + lane * 4);
    float ex0 = hs.x + xr.x, ex1 = hs.y + xr.y, ex2 = hs.z + xr.z, ex3 = hs.w + xr.w;
    ex0 = ex0 > 0.f ? ex0 : 0.2f * ex0;
    ex1 = ex1 > 0.f ? ex1 : 0.2f * ex1;
    ex2 = ex2 > 0.f ? ex2 : 0.2f * ex2;
    ex3 = ex3 > 0.f ? ex3 : 0.2f * ex3;
    float p = av.x * ex0 + av.y * ex1 + av.z * ex2 + av.w * ex3;
    p += __shfl_xor(p, 1);
    p += __shfl_xor(p, 2);
    p += __shfl_xor(p, 4);
    p += __shfl_xor(p, 8);
    // branchless online softmax update (per 16-lane head group, replicated)
    float nm = fmaxf(m, p);
    float so = __expf(m - nm);   // exp(-inf)=0 handles first edge
    float w  = __expf(p - nm);
    den = den * so + w;
    acc.x = acc.x * so + w * hs.x;
    acc.y = acc.y * so + w * hs.y;
    acc.z = acc.z * so + w * hs.z;
    acc.w = acc.w * so + w * hs.w;
    m = nm;
  }
  float r = 1.f / (den + 1e-16f);
  float4 b4 = *reinterpret_cast<const float4*>(bias + lane * 4);
  float4 o4;
  o4.x = acc.x * r + b4.x;
  o4.y = acc.y * r + b4.y;
  o4.z = acc.z * r + b4.z;
  o4.w = acc.w * r + b4.w;
  *reinterpret_cast<float4*>(out + (size_t)wid * HID + lane * 4) = o4;
}

// ----------------------------------------------------------------- launcher
extern "C" void kernel_launch(void* const* d_in, const int* in_sizes, int n_in,
                              void* d_out, int out_size, void* d_ws, size_t ws_size,
                              hipStream_t stream)
{
  const float* x        = (const float*)d_in[0];
  const int*   ei0      = (const int*)d_in[1];
  const int*   ei1      = (const int*)d_in[2];
  const float* pre_W0   = (const float*)d_in[3];
  const float* pre_b0   = (const float*)d_in[4];
  const float* pre_g0   = (const float*)d_in[5];
  const float* pre_be0  = (const float*)d_in[6];
  const float* pre_W1   = (const float*)d_in[7];
  const float* pre_b1   = (const float*)d_in[8];
  const float* pre_g1   = (const float*)d_in[9];
  const float* pre_be1  = (const float*)d_in[10];
  const float* gat_Wl   = (const float*)d_in[11];
  const float* gat_Wr   = (const float*)d_in[12];
  const float* gat_att  = (const float*)d_in[13];
  const float* gat_bias = (const float*)d_in[14];
  const float* proj_W   = (const float*)d_in[15];
  const float* proj_b   = (const float*)d_in[16];
  const float* head_W0  = (const float*)d_in[17];
  const float* head_b0  = (const float*)d_in[18];
  const float* head_W1  = (const float*)d_in[19];
  const float* head_b1  = (const float*)d_in[20];
  float* outp = (float*)d_out;

  // workspace arena
  char* ws = (char*)d_ws;
  float* xlr  = (float*)ws; ws += (size_t)N_NODES * 1024 * 4;   // also used as [N,256] tmp
  float* h    = (float*)ws; ws += (size_t)N_NODES * HID * 4;
  float* outt = (float*)ws; ws += (size_t)N_NODES * HID * 4;
  float* accb = (float*)ws; ws += (size_t)N_NODES * HID * 4;
  float* Wcat = (float*)ws; ws += (size_t)LAYERS * 256 * 1024 * 4;
  int* cnt0  = (int*)ws; ws += (size_t)N_NODES * 4;
  int* cnt1  = (int*)ws; ws += (size_t)N_NODES * 4;
  int* offs0 = (int*)ws; ws += (size_t)(N_NODES + 1) * 4;
  int* offs1 = (int*)ws; ws += (size_t)(N_NODES + 1) * 4;
  int* cur0  = (int*)ws; ws += (size_t)N_NODES * 4;
  int* cur1  = (int*)ws; ws += (size_t)N_NODES * 4;
  int* csr0  = (int*)ws; ws += (size_t)EPRIME * 4;
  int* csr1  = (int*)ws; ws += (size_t)EPRIME * 4;

  // ---- CSR (rebuilt every call; deterministic via per-bucket sort)
  hipMemsetAsync(cnt0, 0, (size_t)N_NODES * 4, stream);
  hipMemsetAsync(cnt1, 0, (size_t)N_NODES * 4, stream);
  int gE = (EPRIME + 255) / 256;
  csr_count<<<gE, 256, 0, stream>>>(ei0, cnt0);
  csr_count<<<gE, 256, 0, stream>>>(ei1, cnt1);
  csr_scan<<<2, 1024, 0, stream>>>(cnt0, offs0, cur0, cnt1, offs1, cur1, N_NODES);
  csr_scatter<<<gE, 256, 0, stream>>>(ei0, cur0, csr0);
  csr_scatter<<<gE, 256, 0, stream>>>(ei1, cur1, csr1);
  csr_sort<<<(N_NODES + 255) / 256, 256, 0, stream>>>(offs0, csr0, N_NODES);
  csr_sort<<<(N_NODES + 255) / 256, 256, 0, stream>>>(offs1, csr1, N_NODES);

  // ---- weight concat for fused Wl|Wr GEMM
  concat_w<<<(LAYERS * 256 * 1024 + 255) / 256, 256, 0, stream>>>(gat_Wl, gat_Wr, Wcat);

  const int gy = (N_NODES + BM - 1) / BM;   // 391
  dim3 blk(256);

  // ---- preprocessor MLP
  gemm_f32<<<dim3(2, gy), blk, 0, stream>>>(x, PRE_IN, pre_W0, HID, xlr, HID,
                                            nullptr, pre_b0, N_NODES, HID, PRE_IN, 0);
  ln_relu<<<(N_NODES * 64 + 255) / 256, 256, 0, stream>>>(xlr, h, pre_g0, pre_be0, N_NODES);
  gemm_f32<<<dim3(2, gy), blk, 0, stream>>>(h, HID, pre_W1, HID, xlr, HID,
                                            nullptr, pre_b1, N_NODES, HID, HID, 0);
  ln_relu<<<(N_NODES * 64 + 255) / 256, 256, 0, stream>>>(xlr, h, pre_g1, pre_be1, N_NODES);

  // ---- GNN layers
  for (int l = 0; l < LAYERS; l++) {
    gemm_f32<<<dim3(8, gy), blk, 0, stream>>>(h, HID, Wcat + (size_t)l * 256 * 1024, 1024,
                                              xlr, 1024, nullptr, nullptr,
                                              N_NODES, 1024, HID, 0);
    for (int t = 0; t < NTYPES; t++) {
      const int* offs = t ? offs1 : offs0;
      const int* csr  = t ? csr1 : csr0;
      gat_edge<<<(N_NODES * 64 + 255) / 256, 256, 0, stream>>>(
          xlr, offs, csr,
          gat_att  + ((size_t)l * NTYPES + t) * NHEAD * DHEAD,
          gat_bias + ((size_t)l * NTYPES + t) * HID,
          outt, N_NODES, t * 512, t * 512 + 256);
      const float* Wp = proj_W + ((size_t)l * NTYPES + t) * HID * HID;
      const float* bp = proj_b + ((size_t)l * NTYPES + t) * HID;
      if (t == 0)
        gemm_f32<<<dim3(2, gy), blk, 0, stream>>>(outt, HID, Wp, HID, accb, HID,
                                                  nullptr, bp, N_NODES, HID, HID, 0);
      else
        gemm_f32<<<dim3(2, gy), blk, 0, stream>>>(outt, HID, Wp, HID, h, HID,
                                                  accb, bp, N_NODES, HID, HID, 1);
    }
  }

  // ---- prediction head
  gemm_f32<<<dim3(2, gy), blk, 0, stream>>>(h, HID, head_W0, HID, xlr, HID,
                                            nullptr, head_b0, N_NODES, HID, HID, 1);
  gemm_f32<<<dim3(1, gy), blk, 0, stream>>>(xlr, HID, head_W1, OUT_DIM, outp, OUT_DIM,
                                            nullptr, head_b1, N_NODES, OUT_DIM, HID, 0);
}

// Round 2
// 1337.215 us; speedup vs baseline: 1.9250x; 1.9250x over previous
//
#include <hip/hip_runtime.h>
#include <hip/hip_bf16.h>
#include <math.h>

#define N_NODES 50000
#define MP      50048          // 391 * 128, padded row count
#define E_EDGES 500000
#define EPRIME  (E_EDGES + N_NODES)
#define HID     256
#define PRE_IN  1024
#define OUT_DIM 64
#define NHEAD   4
#define DHEAD   64
#define LAYERS  2
#define NTYPES  2

typedef __attribute__((ext_vector_type(8))) short short8v;
typedef __attribute__((ext_vector_type(4))) float f32x4;

__device__ __forceinline__ ushort f2bf(float f) {
  uint u = __float_as_uint(f);
  u += 0x7FFF + ((u >> 16) & 1);          // RNE
  return (ushort)(u >> 16);
}
__device__ __forceinline__ float bf2f(ushort u) {
  return __uint_as_float(((uint)u) << 16);
}

// ------------------------------------------------------------- bf16 MFMA GEMM
// C[M,N] = op(A[M,K] @ Bt[N,K]^T + bias + Cin); A,Bt bf16 K-major, rows padded.
// 128x128 tile, BK=32, 4 waves of 64x64, mfma_f32_16x16x32_bf16.
// LDS layout [row][kc-slot]: byte = row*64 + (kc ^ ((row>>1)&3))*16  (XOR swizzle,
// applied on BOTH the pre-swizzled global_load_lds source and the ds_read).
__global__ __launch_bounds__(256) void gemm_bf16(
    const ushort* __restrict__ A,
    const ushort* __restrict__ Bt,
    int K, int M, int N,
    float*  __restrict__ Cf,          // f32 out (or null)
    ushort* __restrict__ Cb,          // bf16 out (or null)
    const float* __restrict__ Cin,    // f32 accumulate-in (or null), stride N
    const float* __restrict__ bias,   // [N] or null
    int do_relu)
{
  __shared__ ushort As[128 * 32];
  __shared__ ushort Bs[128 * 32];
  const int tid = threadIdx.x;
  const int l   = tid & 63;
  const int w   = tid >> 6;
  const int wm  = w & 1;
  const int wn  = w >> 1;
  const int bm  = blockIdx.y * 128;
  const int bn  = blockIdx.x * 128;

  f32x4 acc[4][4];
#pragma unroll
  for (int m = 0; m < 4; m++)
#pragma unroll
    for (int n = 0; n < 4; n++) acc[m][n] = (f32x4){0.f, 0.f, 0.f, 0.f};

  const int srow  = l >> 2;   // 0..15 within a 16-row group
  const int sslot = l & 3;    // kc slot

  for (int k0 = 0; k0 < K; k0 += 32) {
    // ---- stage A,B tiles: wave w covers rows [w*32, w*32+32)
#pragma unroll
    for (int i = 0; i < 2; i++) {
      const int row = w * 32 + i * 16 + srow;
      const int kc  = sslot ^ ((row >> 1) & 3);     // inverse-swizzled source
      const ushort* ga = A  + (size_t)(bm + row) * K + k0 + kc * 8;
      const ushort* gb = Bt + (size_t)(bn + row) * K + k0 + kc * 8;
      const uint off = (uint)row * 64 + (uint)sslot * 16;  // == wave_base + l*16
      __builtin_amdgcn_global_load_lds(
          (const __attribute__((address_space(1))) uint*)ga,
          (__attribute__((address_space(3))) uint*)((char*)As + off), 16, 0, 0);
      __builtin_amdgcn_global_load_lds(
          (const __attribute__((address_space(1))) uint*)gb,
          (__attribute__((address_space(3))) uint*)((char*)Bs + off), 16, 0, 0);
    }
    __syncthreads();   // compiler emits s_waitcnt vmcnt(0) before s_barrier

    short8v a[4], b[4];
#pragma unroll
    for (int m = 0; m < 4; m++) {
      const int row = wm * 64 + m * 16 + (l & 15);
      const int kc  = (l >> 4) ^ ((row >> 1) & 3);
      a[m] = *(const short8v*)((const char*)As + row * 64 + kc * 16);
    }
#pragma unroll
    for (int n = 0; n < 4; n++) {
      const int row = wn * 64 + n * 16 + (l & 15);
      const int kc  = (l >> 4) ^ ((row >> 1) & 3);
      b[n] = *(const short8v*)((const char*)Bs + row * 64 + kc * 16);
    }
#pragma unroll
    for (int m = 0; m < 4; m++)
#pragma unroll
      for (int n = 0; n < 4; n++)
        acc[m][n] = __builtin_amdgcn_mfma_f32_16x16x32_bf16(a[m], b[n], acc[m][n], 0, 0, 0);
    __syncthreads();
  }

  // ---- epilogue: C/D map col=lane&15, row=(lane>>4)*4+reg
  const int crow0 = bm + wm * 64 + (l >> 4) * 4;
  const int ccol0 = bn + wn * 64 + (l & 15);
#pragma unroll
  for (int m = 0; m < 4; m++) {
#pragma unroll
    for (int j = 0; j < 4; j++) {
      const int grow = crow0 + m * 16 + j;
      if (grow < M) {
#pragma unroll
        for (int n = 0; n < 4; n++) {
          const int gcol = ccol0 + n * 16;
          if (gcol < N) {
            float v = acc[m][n][j];
            if (bias) v += bias[gcol];
            if (Cin)  v += Cin[(size_t)grow * N + gcol];
            if (do_relu) v = fmaxf(v, 0.f);
            if (Cf) Cf[(size_t)grow * N + gcol] = v;
            else    Cb[(size_t)grow * N + gcol] = f2bf(v);
          }
        }
      }
    }
  }
}

// ------------------------------------------------------------ LayerNorm+ReLU
// in: f32 [n,256]; out: bf16 [*,256]; one wave per row
__global__ void ln_relu(const float* __restrict__ in, ushort* __restrict__ out,
                        const float* __restrict__ g, const float* __restrict__ be, int n)
{
  int gid = blockIdx.x * blockDim.x + threadIdx.x;
  int row = gid >> 6;
  int lane = threadIdx.x & 63;
  if (row >= n) return;
  float4 v = *reinterpret_cast<const float4*>(in + (size_t)row * HID + lane * 4);
  float s = v.x + v.y + v.z + v.w;
  float ss = v.x * v.x + v.y * v.y + v.z * v.z + v.w * v.w;
#pragma unroll
  for (int o = 1; o < 64; o <<= 1) { s += __shfl_xor(s, o); ss += __shfl_xor(ss, o); }
  float mu = s * (1.f / 256.f);
  float var = ss * (1.f / 256.f) - mu * mu;
  float inv = rsqrtf(var + 1e-5f);
  float4 gg = *reinterpret_cast<const float4*>(g + lane * 4);
  float4 bb = *reinterpret_cast<const float4*>(be + lane * 4);
  ushort4 o4;
  o4.x = f2bf(fmaxf((v.x - mu) * inv * gg.x + bb.x, 0.f));
  o4.y = f2bf(fmaxf((v.y - mu) * inv * gg.y + bb.y, 0.f));
  o4.z = f2bf(fmaxf((v.z - mu) * inv * gg.z + bb.z, 0.f));
  o4.w = f2bf(fmaxf((v.w - mu) * inv * gg.w + bb.w, 0.f));
  *reinterpret_cast<ushort4*>(out + (size_t)row * HID + lane * 4) = o4;
}

// ------------------------------------------------------------- CSR building
__global__ void csr_count(const int* __restrict__ ei, int* __restrict__ count)
{
  int e = blockIdx.x * blockDim.x + threadIdx.x;
  if (e >= EPRIME) return;
  int d = (e < E_EDGES) ? ei[E_EDGES + e] : (e - E_EDGES);
  atomicAdd(&count[d], 1);
}

__global__ __launch_bounds__(1024) void csr_scan(
    int* __restrict__ c0, int* __restrict__ o0, int* __restrict__ u0,
    int* __restrict__ c1, int* __restrict__ o1, int* __restrict__ u1, int n)
{
  int* count = blockIdx.x ? c1 : c0;
  int* offs  = blockIdx.x ? o1 : o0;
  int* cur   = blockIdx.x ? u1 : u0;
  __shared__ int partial[1024];
  int tid = threadIdx.x;
  int chunk = (n + 1023) / 1024;
  int b = tid * chunk;
  int s = 0;
  for (int i = 0; i < chunk; i++) { int idx = b + i; if (idx < n) s += count[idx]; }
  partial[tid] = s;
  __syncthreads();
  for (int o = 1; o < 1024; o <<= 1) {
    int v = (tid >= o) ? partial[tid - o] : 0;
    __syncthreads();
    partial[tid] += v;
    __syncthreads();
  }
  int run = (tid == 0) ? 0 : partial[tid - 1];
  for (int i = 0; i < chunk; i++) {
    int idx = b + i;
    if (idx < n) { offs[idx] = run; cur[idx] = run; run += count[idx]; }
  }
  if (tid == 1023) offs[n] = partial[1023];
}

__global__ void csr_scatter(const int* __restrict__ ei, int* __restrict__ cur,
                            int* __restrict__ csr_src)
{
  int e = blockIdx.x * blockDim.x + threadIdx.x;
  if (e >= EPRIME) return;
  int d = (e < E_EDGES) ? ei[E_EDGES + e] : (e - E_EDGES);
  int s = (e < E_EDGES) ? ei[e] : (e - E_EDGES);
  int pos = atomicAdd(&cur[d], 1);
  csr_src[pos] = s;
}

__global__ void csr_sort(const int* __restrict__ offs, int* __restrict__ csr_src, int n)
{
  int d = blockIdx.x * blockDim.x + threadIdx.x;
  if (d >= n) return;
  int b = offs[d], e = offs[d + 1];
  for (int i = b + 1; i < e; i++) {
    int v = csr_src[i];
    int j = i - 1;
    while (j >= b && csr_src[j] > v) { csr_src[j + 1] = csr_src[j]; j--; }
    csr_src[j + 1] = v;
  }
}

// --------------------------------------------- weight transpose/cast to bf16
// W [K][Nc] f32 -> Wt [NrPad][K] bf16 (K-major), zero pad rows
__global__ void wtrans(const float* __restrict__ W, ushort* __restrict__ Wt,
                       int K, int Nc, int NrPad)
{
  int i = blockIdx.x * blockDim.x + threadIdx.x;
  if (i >= NrPad * K) return;
  int nrow = i / K, k = i - nrow * K;
  Wt[i] = (nrow < Nc) ? f2bf(W[(size_t)k * Nc + nrow]) : (ushort)0;
}

// WcatT [L][1024][256] bf16: row c = (t,half,cc) -> (half?Wr:Wl)[l][t][k][cc]
__global__ void wcat_trans(const float* __restrict__ Wl, const float* __restrict__ Wr,
                           ushort* __restrict__ out)
{
  int i = blockIdx.x * blockDim.x + threadIdx.x;
  if (i >= LAYERS * 1024 * 256) return;
  int l = i >> 18;
  int rem = i & 262143;
  int c = rem >> 8;
  int k = rem & 255;
  int t = c >> 9, half = (c >> 8) & 1, cc = c & 255;
  const float* W = half ? Wr : Wl;
  out[i] = f2bf(W[(((size_t)l * NTYPES + t) * 256 + k) * 256 + cc]);
}

// ---------------------------------------------------- x f32 -> bf16 cast
__global__ void cast_bf16(const float* __restrict__ in, ushort* __restrict__ out, int n4)
{
  int i = blockIdx.x * blockDim.x + threadIdx.x;
  if (i >= n4) return;
  float4 v = reinterpret_cast<const float4*>(in)[i];
  ushort4 o;
  o.x = f2bf(v.x); o.y = f2bf(v.y); o.z = f2bf(v.z); o.w = f2bf(v.w);
  reinterpret_cast<ushort4*>(out)[i] = o;
}

// ---------------------------------------------- GATv2: dst-centric online SM
// one wave per dst node; lane owns 4 channels (head = lane/16); bf16 in/out
__global__ void gat_edge(const ushort* __restrict__ xlr,      // [MP,1024] bf16
                         const int* __restrict__ offs,
                         const int* __restrict__ csr_src,
                         const float* __restrict__ att,       // [256]
                         const float* __restrict__ bias,      // [256]
                         ushort* __restrict__ out,            // [MP,256] bf16
                         int n, int xl_col, int xr_col)
{
  int gid = blockIdx.x * blockDim.x + threadIdx.x;
  int wid = gid >> 6;
  int lane = threadIdx.x & 63;
  if (wid >= n) return;

  ushort4 xru = *reinterpret_cast<const ushort4*>(xlr + (size_t)wid * 1024 + xr_col + lane * 4);
  const float xr0 = bf2f(xru.x), xr1 = bf2f(xru.y), xr2 = bf2f(xru.z), xr3 = bf2f(xru.w);
  const float4 av = *reinterpret_cast<const float4*>(att + lane * 4);
  int beg = offs[wid], end = offs[wid + 1];

  float m = -INFINITY, den = 0.f;
  float a0 = 0.f, a1 = 0.f, a2 = 0.f, a3 = 0.f;

  for (int j = beg; j < end; j++) {
    int s = csr_src[j];
    ushort4 hsu = *reinterpret_cast<const ushort4*>(xlr + (size_t)s * 1024 + xl_col + lane * 4);
    float h0 = bf2f(hsu.x), h1 = bf2f(hsu.y), h2 = bf2f(hsu.z), h3 = bf2f(hsu.w);
    float e0 = h0 + xr0, e1 = h1 + xr1, e2 = h2 + xr2, e3 = h3 + xr3;
    e0 = e0 > 0.f ? e0 : 0.2f * e0;
    e1 = e1 > 0.f ? e1 : 0.2f * e1;
    e2 = e2 > 0.f ? e2 : 0.2f * e2;
    e3 = e3 > 0.f ? e3 : 0.2f * e3;
    float p = av.x * e0 + av.y * e1 + av.z * e2 + av.w * e3;
    p += __shfl_xor(p, 1);
    p += __shfl_xor(p, 2);
    p += __shfl_xor(p, 4);
    p += __shfl_xor(p, 8);
    float nm = fmaxf(m, p);
    float so = __expf(m - nm);
    float wgt = __expf(p - nm);
    den = den * so + wgt;
    a0 = a0 * so + wgt * h0;
    a1 = a1 * so + wgt * h1;
    a2 = a2 * so + wgt * h2;
    a3 = a3 * so + wgt * h3;
    m = nm;
  }
  float r = 1.f / (den + 1e-16f);
  const float4 b4 = *reinterpret_cast<const float4*>(bias + lane * 4);
  ushort4 o4;
  o4.x = f2bf(a0 * r + b4.x);
  o4.y = f2bf(a1 * r + b4.y);
  o4.z = f2bf(a2 * r + b4.z);
  o4.w = f2bf(a3 * r + b4.w);
  *reinterpret_cast<ushort4*>(out + (size_t)wid * HID + lane * 4) = o4;
}

// ----------------------------------------------------------------- launcher
extern "C" void kernel_launch(void* const* d_in, const int* in_sizes, int n_in,
                              void* d_out, int out_size, void* d_ws, size_t ws_size,
                              hipStream_t stream)
{
  const float* x        = (const float*)d_in[0];
  const int*   ei0      = (const int*)d_in[1];
  const int*   ei1      = (const int*)d_in[2];
  const float* pre_W0   = (const float*)d_in[3];
  const float* pre_b0   = (const float*)d_in[4];
  const float* pre_g0   = (const float*)d_in[5];
  const float* pre_be0  = (const float*)d_in[6];
  const float* pre_W1   = (const float*)d_in[7];
  const float* pre_b1   = (const float*)d_in[8];
  const float* pre_g1   = (const float*)d_in[9];
  const float* pre_be1  = (const float*)d_in[10];
  const float* gat_Wl   = (const float*)d_in[11];
  const float* gat_Wr   = (const float*)d_in[12];
  const float* gat_att  = (const float*)d_in[13];
  const float* gat_bias = (const float*)d_in[14];
  const float* proj_W   = (const float*)d_in[15];
  const float* proj_b   = (const float*)d_in[16];
  const float* head_W0  = (const float*)d_in[17];
  const float* head_b0  = (const float*)d_in[18];
  const float* head_W1  = (const float*)d_in[19];
  const float* head_b1  = (const float*)d_in[20];
  float* outp = (float*)d_out;

  // ---- workspace arena (all segment sizes multiples of 512 B until ints)
  char* ws = (char*)d_ws;
  ushort* xlr_b = (ushort*)ws; ws += (size_t)MP * 1024 * 2;   // also xb for pre0
  ushort* hb    = (ushort*)ws; ws += (size_t)MP * HID * 2;
  ushort* outt  = (ushort*)ws; ws += (size_t)MP * HID * 2;
  float*  tmp   = (float*)ws;  ws += (size_t)MP * HID * 4;    // pre-LN buf / accb
  ushort* W0t   = (ushort*)ws; ws += (size_t)256 * 1024 * 2;
  ushort* W1t   = (ushort*)ws; ws += (size_t)256 * 256 * 2;
  ushort* WcatT = (ushort*)ws; ws += (size_t)LAYERS * 1024 * 256 * 2;
  ushort* projT = (ushort*)ws; ws += (size_t)LAYERS * NTYPES * 256 * 256 * 2;
  ushort* hW0t  = (ushort*)ws; ws += (size_t)256 * 256 * 2;
  ushort* hW1t  = (ushort*)ws; ws += (size_t)128 * 256 * 2;
  int* cnt0  = (int*)ws; ws += (size_t)N_NODES * 4;
  int* cnt1  = (int*)ws; ws += (size_t)N_NODES * 4;
  int* offs0 = (int*)ws; ws += (size_t)(N_NODES + 1) * 4;
  int* offs1 = (int*)ws; ws += (size_t)(N_NODES + 1) * 4;
  int* cur0  = (int*)ws; ws += (size_t)N_NODES * 4;
  int* cur1  = (int*)ws; ws += (size_t)N_NODES * 4;
  int* csr0  = (int*)ws; ws += (size_t)EPRIME * 4;
  int* csr1  = (int*)ws; ws += (size_t)EPRIME * 4;

  // ---- CSR build (deterministic via per-bucket sort)
  hipMemsetAsync(cnt0, 0, (size_t)N_NODES * 4, stream);
  hipMemsetAsync(cnt1, 0, (size_t)N_NODES * 4, stream);
  int gE = (EPRIME + 255) / 256;
  csr_count<<<gE, 256, 0, stream>>>(ei0, cnt0);
  csr_count<<<gE, 256, 0, stream>>>(ei1, cnt1);
  csr_scan<<<2, 1024, 0, stream>>>(cnt0, offs0, cur0, cnt1, offs1, cur1, N_NODES);
  csr_scatter<<<gE, 256, 0, stream>>>(ei0, cur0, csr0);
  csr_scatter<<<gE, 256, 0, stream>>>(ei1, cur1, csr1);
  csr_sort<<<(N_NODES + 255) / 256, 256, 0, stream>>>(offs0, csr0, N_NODES);
  csr_sort<<<(N_NODES + 255) / 256, 256, 0, stream>>>(offs1, csr1, N_NODES);

  // ---- weights -> bf16 K-major
  wtrans<<<(256 * 1024 + 255) / 256, 256, 0, stream>>>(pre_W0, W0t, 1024, 256, 256);
  wtrans<<<(256 * 256 + 255) / 256, 256, 0, stream>>>(pre_W1, W1t, 256, 256, 256);
  wcat_trans<<<(LAYERS * 1024 * 256 + 255) / 256, 256, 0, stream>>>(gat_Wl, gat_Wr, WcatT);
  for (int lt = 0; lt < LAYERS * NTYPES; lt++)
    wtrans<<<(256 * 256 + 255) / 256, 256, 0, stream>>>(
        proj_W + (size_t)lt * 256 * 256, projT + (size_t)lt * 256 * 256, 256, 256, 256);
  wtrans<<<(256 * 256 + 255) / 256, 256, 0, stream>>>(head_W0, hW0t, 256, 256, 256);
  wtrans<<<(128 * 256 + 255) / 256, 256, 0, stream>>>(head_W1, hW1t, 256, 64, 128);

  // ---- x -> bf16 (into xlr_b, dead by the time layer GEMMs write it)
  cast_bf16<<<(N_NODES * 1024 / 4 + 255) / 256, 256, 0, stream>>>(x, xlr_b, N_NODES * 1024 / 4);

  const dim3 blk(256);
  const int gy = MP / 128;   // 391
  const int gln = (N_NODES * 64 + 255) / 256;

  // ---- preprocessor MLP
  gemm_bf16<<<dim3(2, gy), blk, 0, stream>>>(xlr_b, W0t, 1024, N_NODES, 256,
                                             tmp, nullptr, nullptr, pre_b0, 0);
  ln_relu<<<gln, 256, 0, stream>>>(tmp, hb, pre_g0, pre_be0, N_NODES);
  gemm_bf16<<<dim3(2, gy), blk, 0, stream>>>(hb, W1t, 256, N_NODES, 256,
                                             tmp, nullptr, nullptr, pre_b1, 0);
  ln_relu<<<gln, 256, 0, stream>>>(tmp, hb, pre_g1, pre_be1, N_NODES);

  // ---- GNN layers
  for (int l = 0; l < LAYERS; l++) {
    gemm_bf16<<<dim3(8, gy), blk, 0, stream>>>(hb, WcatT + (size_t)l * 1024 * 256,
                                               256, N_NODES, 1024,
                                               nullptr, xlr_b, nullptr, nullptr, 0);
    for (int t = 0; t < NTYPES; t++) {
      const int* offs = t ? offs1 : offs0;
      const int* csr  = t ? csr1 : csr0;
      gat_edge<<<gln, 256, 0, stream>>>(
          xlr_b, offs, csr,
          gat_att  + ((size_t)l * NTYPES + t) * NHEAD * DHEAD,
          gat_bias + ((size_t)l * NTYPES + t) * HID,
          outt, N_NODES, t * 512, t * 512 + 256);
      const ushort* Wp = projT + ((size_t)l * NTYPES + t) * 256 * 256;
      const float*  bp = proj_b + ((size_t)l * NTYPES + t) * HID;
      if (t == 0)
        gemm_bf16<<<dim3(2, gy), blk, 0, stream>>>(outt, Wp, 256, N_NODES, 256,
                                                   tmp, nullptr, nullptr, bp, 0);
      else
        gemm_bf16<<<dim3(2, gy), blk, 0, stream>>>(outt, Wp, 256, N_NODES, 256,
                                                   nullptr, hb, tmp, bp, 1);
    }
  }

  // ---- prediction head
  gemm_bf16<<<dim3(2, gy), blk, 0, stream>>>(hb, hW0t, 256, N_NODES, 256,
                                             nullptr, outt, nullptr, head_b0, 1);
  gemm_bf16<<<dim3(1, gy), blk, 0, stream>>>(outt, hW1t, 256, N_NODES, OUT_DIM,
                                             outp, nullptr, nullptr, head_b1, 0);
}

// Round 3
// 1054.519 us; speedup vs baseline: 2.4411x; 1.2681x over previous
//
#include <hip/hip_runtime.h>
#include <hip/hip_bf16.h>
#include <math.h>

#define N_NODES 50000
#define MP      50048          // 391 * 128, padded row count
#define E_EDGES 500000
#define EPRIME  (E_EDGES + N_NODES)
#define HID     256
#define PRE_IN  1024
#define OUT_DIM 64
#define NHEAD   4
#define DHEAD   64
#define LAYERS  2
#define NTYPES  2

#define SCAN_NBLK 49                     // ceil(50000/1024)
#define NPAD      (SCAN_NBLK * 1024)     // 50176

typedef __attribute__((ext_vector_type(8))) short short8v;
typedef __attribute__((ext_vector_type(4))) float f32x4;

__device__ __forceinline__ ushort f2bf(float f) {
  uint u = __float_as_uint(f);
  u += 0x7FFF + ((u >> 16) & 1);          // RNE
  return (ushort)(u >> 16);
}
__device__ __forceinline__ float bf2f(ushort u) {
  return __uint_as_float(((uint)u) << 16);
}

// ------------------------------------------------------------- bf16 MFMA GEMM
// C[M,N] = op(A[M,K] @ Bt[N,K]^T + bias(+bias2) ); Bt bf16 K-major, rows padded.
// A: bf16 K-major (AF32=false) or f32 K-major (AF32=true, rows >= M read as 0).
// 128x128 tile, BK=32, 4 waves of 64x64, mfma_f32_16x16x32_bf16.
// LDS layout byte = row*64 + (kc ^ ((row>>1)&3))*16 (XOR swizzle on both sides).
template<bool AF32>
__global__ __launch_bounds__(256) void gemm_k(
    const void* __restrict__ Ap,
    const ushort* __restrict__ Bt,
    int K, int M, int N,
    float*  __restrict__ Cf,          // f32 out (or null)
    ushort* __restrict__ Cb,          // bf16 out (or null)
    const float* __restrict__ bias,   // [N] or null
    const float* __restrict__ bias2,  // [N] or null (added too)
    int do_relu)
{
  __shared__ ushort As[128 * 32];
  __shared__ ushort Bs[128 * 32];
  const int tid = threadIdx.x;
  const int l   = tid & 63;
  const int w   = tid >> 6;
  const int wm  = w & 1;
  const int wn  = w >> 1;
  const int bm  = blockIdx.y * 128;
  const int bn  = blockIdx.x * 128;

  f32x4 acc[4][4];
#pragma unroll
  for (int m = 0; m < 4; m++)
#pragma unroll
    for (int n = 0; n < 4; n++) acc[m][n] = (f32x4){0.f, 0.f, 0.f, 0.f};

  const int srow  = l >> 2;   // 0..15
  const int sslot = l & 3;    // kc slot

  for (int k0 = 0; k0 < K; k0 += 32) {
#pragma unroll
    for (int i = 0; i < 2; i++) {
      const int row = w * 32 + i * 16 + srow;
      const int kc  = sslot ^ ((row >> 1) & 3);     // inverse-swizzled source
      const uint off = (uint)row * 64 + (uint)sslot * 16;  // wave base + l*16
      const ushort* gb = Bt + (size_t)(bn + row) * K + k0 + kc * 8;
      __builtin_amdgcn_global_load_lds(
          (const __attribute__((address_space(1))) uint*)gb,
          (__attribute__((address_space(3))) uint*)((char*)Bs + off), 16, 0, 0);
      if constexpr (AF32) {
        const float* ga = (const float*)Ap + (size_t)(bm + row) * K + k0 + kc * 8;
        float4 v0 = make_float4(0.f, 0.f, 0.f, 0.f);
        float4 v1 = make_float4(0.f, 0.f, 0.f, 0.f);
        if (bm + row < M) {
          v0 = *reinterpret_cast<const float4*>(ga);
          v1 = *reinterpret_cast<const float4*>(ga + 4);
        }
        short8v s;
        s[0] = (short)f2bf(v0.x); s[1] = (short)f2bf(v0.y);
        s[2] = (short)f2bf(v0.z); s[3] = (short)f2bf(v0.w);
        s[4] = (short)f2bf(v1.x); s[5] = (short)f2bf(v1.y);
        s[6] = (short)f2bf(v1.z); s[7] = (short)f2bf(v1.w);
        *reinterpret_cast<short8v*>((char*)As + off) = s;
      } else {
        const ushort* ga = (const ushort*)Ap + (size_t)(bm + row) * K + k0 + kc * 8;
        __builtin_amdgcn_global_load_lds(
            (const __attribute__((address_space(1))) uint*)ga,
            (__attribute__((address_space(3))) uint*)((char*)As + off), 16, 0, 0);
      }
    }
    __syncthreads();

    short8v a[4], b[4];
#pragma unroll
    for (int m = 0; m < 4; m++) {
      const int row = wm * 64 + m * 16 + (l & 15);
      const int kc  = (l >> 4) ^ ((row >> 1) & 3);
      a[m] = *(const short8v*)((const char*)As + row * 64 + kc * 16);
    }
#pragma unroll
    for (int n = 0; n < 4; n++) {
      const int row = wn * 64 + n * 16 + (l & 15);
      const int kc  = (l >> 4) ^ ((row >> 1) & 3);
      b[n] = *(const short8v*)((const char*)Bs + row * 64 + kc * 16);
    }
#pragma unroll
    for (int m = 0; m < 4; m++)
#pragma unroll
      for (int n = 0; n < 4; n++)
        acc[m][n] = __builtin_amdgcn_mfma_f32_16x16x32_bf16(a[m], b[n], acc[m][n], 0, 0, 0);
    __syncthreads();
  }

  // epilogue: C/D map col=lane&15, row=(lane>>4)*4+reg
  const int crow0 = bm + wm * 64 + (l >> 4) * 4;
  const int ccol0 = bn + wn * 64 + (l & 15);
#pragma unroll
  for (int m = 0; m < 4; m++) {
#pragma unroll
    for (int j = 0; j < 4; j++) {
      const int grow = crow0 + m * 16 + j;
      if (grow < M) {
#pragma unroll
        for (int n = 0; n < 4; n++) {
          const int gcol = ccol0 + n * 16;
          if (gcol < N) {
            float v = acc[m][n][j];
            if (bias)  v += bias[gcol];
            if (bias2) v += bias2[gcol];
            if (do_relu) v = fmaxf(v, 0.f);
            if (Cf) Cf[(size_t)grow * N + gcol] = v;
            else    Cb[(size_t)grow * N + gcol] = f2bf(v);
          }
        }
      }
    }
  }
}

// ------------------------------------------------------------ LayerNorm+ReLU
__global__ void ln_relu(const float* __restrict__ in, ushort* __restrict__ out,
                        const float* __restrict__ g, const float* __restrict__ be, int n)
{
  int gid = blockIdx.x * blockDim.x + threadIdx.x;
  int row = gid >> 6;
  int lane = threadIdx.x & 63;
  if (row >= n) return;
  float4 v = *reinterpret_cast<const float4*>(in + (size_t)row * HID + lane * 4);
  float s = v.x + v.y + v.z + v.w;
  float ss = v.x * v.x + v.y * v.y + v.z * v.z + v.w * v.w;
#pragma unroll
  for (int o = 1; o < 64; o <<= 1) { s += __shfl_xor(s, o); ss += __shfl_xor(ss, o); }
  float mu = s * (1.f / 256.f);
  float var = ss * (1.f / 256.f) - mu * mu;
  float inv = rsqrtf(var + 1e-5f);
  float4 gg = *reinterpret_cast<const float4*>(g + lane * 4);
  float4 bb = *reinterpret_cast<const float4*>(be + lane * 4);
  ushort4 o4;
  o4.x = f2bf(fmaxf((v.x - mu) * inv * gg.x + bb.x, 0.f));
  o4.y = f2bf(fmaxf((v.y - mu) * inv * gg.y + bb.y, 0.f));
  o4.z = f2bf(fmaxf((v.z - mu) * inv * gg.z + bb.z, 0.f));
  o4.w = f2bf(fmaxf((v.w - mu) * inv * gg.w + bb.w, 0.f));
  *reinterpret_cast<ushort4*>(out + (size_t)row * HID + lane * 4) = o4;
}

// ------------------------------------------------------------- CSR building
__global__ void csr_count2(const int* __restrict__ ei0, const int* __restrict__ ei1,
                           int* __restrict__ cnt0, int* __restrict__ cnt1)
{
  int e = blockIdx.x * blockDim.x + threadIdx.x;
  if (e >= 2 * EPRIME) return;
  int type = e >= EPRIME;
  int i = type ? e - EPRIME : e;
  const int* ei = type ? ei1 : ei0;
  int* cnt = type ? cnt1 : cnt0;
  int d = (i < E_EDGES) ? ei[E_EDGES + i] : (i - E_EDGES);
  atomicAdd(&cnt[d], 1);
}

// --- hierarchical exclusive scan over cnt0,cnt1 (padded to NPAD with zeros)
__global__ __launch_bounds__(256) void scan_p1(const int* __restrict__ cnt0,
                                               const int* __restrict__ cnt1,
                                               int* __restrict__ bsums)
{
  int type = blockIdx.x >= SCAN_NBLK;
  int blk = type ? blockIdx.x - SCAN_NBLK : blockIdx.x;
  const int* cnt = type ? cnt1 : cnt0;
  int4 v = reinterpret_cast<const int4*>(cnt)[blk * 256 + threadIdx.x];
  int s = v.x + v.y + v.z + v.w;
#pragma unroll
  for (int o = 1; o < 64; o <<= 1) s += __shfl_xor(s, o);
  __shared__ int wt[4];
  if ((threadIdx.x & 63) == 0) wt[threadIdx.x >> 6] = s;
  __syncthreads();
  if (threadIdx.x == 0) bsums[blockIdx.x] = wt[0] + wt[1] + wt[2] + wt[3];
}

__global__ void scan_p2(const int* __restrict__ bsums, int* __restrict__ boffs,
                        int* __restrict__ offs0, int* __restrict__ offs1)
{
  int t = threadIdx.x;
  if (t < 2) {
    int run = 0;
    for (int i = 0; i < SCAN_NBLK; i++) {
      boffs[t * SCAN_NBLK + i] = run;
      run += bsums[t * SCAN_NBLK + i];
    }
  }
  if (t == 2) offs0[N_NODES] = EPRIME;
  if (t == 3) offs1[N_NODES] = EPRIME;
}

__global__ __launch_bounds__(256) void scan_p3(
    const int* __restrict__ cnt0, const int* __restrict__ cnt1,
    const int* __restrict__ boffs,
    int* __restrict__ offs0, int* __restrict__ cur0,
    int* __restrict__ offs1, int* __restrict__ cur1)
{
  int type = blockIdx.x >= SCAN_NBLK;
  int blk = type ? blockIdx.x - SCAN_NBLK : blockIdx.x;
  const int* cnt = type ? cnt1 : cnt0;
  int* offs = type ? offs1 : offs0;
  int* cur  = type ? cur1 : cur0;
  const int tid = threadIdx.x, lane = tid & 63, wv = tid >> 6;
  int4 v = reinterpret_cast<const int4*>(cnt)[blk * 256 + tid];
  int e1 = v.x, e2 = e1 + v.y, e3 = e2 + v.z, T = e3 + v.w;
  int incl = T;
#pragma unroll
  for (int o = 1; o < 64; o <<= 1) {
    int nb = __shfl_up(incl, o);
    if (lane >= o) incl += nb;
  }
  __shared__ int wt[4];
  if (lane == 63) wt[wv] = incl;
  __syncthreads();
  int wexcl = 0;
  for (int i = 0; i < wv; i++) wexcl += wt[i];
  int base = boffs[blockIdx.x] + wexcl + (incl - T);
  int idx = blk * 1024 + tid * 4;
  int4 o4 = make_int4(base, base + e1, base + e2, base + e3);
  if (idx + 3 < N_NODES) {
    reinterpret_cast<int4*>(offs)[idx >> 2] = o4;
    reinterpret_cast<int4*>(cur)[idx >> 2] = o4;
  } else {
    if (idx + 0 < N_NODES) { offs[idx + 0] = o4.x; cur[idx + 0] = o4.x; }
    if (idx + 1 < N_NODES) { offs[idx + 1] = o4.y; cur[idx + 1] = o4.y; }
    if (idx + 2 < N_NODES) { offs[idx + 2] = o4.z; cur[idx + 2] = o4.z; }
    if (idx + 3 < N_NODES) { offs[idx + 3] = o4.w; cur[idx + 3] = o4.w; }
  }
}

__global__ void csr_scatter2(const int* __restrict__ ei0, const int* __restrict__ ei1,
                             int* __restrict__ cur0, int* __restrict__ cur1,
                             int* __restrict__ csr0, int* __restrict__ csr1)
{
  int e = blockIdx.x * blockDim.x + threadIdx.x;
  if (e >= 2 * EPRIME) return;
  int type = e >= EPRIME;
  int i = type ? e - EPRIME : e;
  const int* ei = type ? ei1 : ei0;
  int* cur = type ? cur1 : cur0;
  int* csr = type ? csr1 : csr0;
  int d = (i < E_EDGES) ? ei[E_EDGES + i] : (i - E_EDGES);
  int s = (i < E_EDGES) ? ei[i] : (i - E_EDGES);
  int pos = atomicAdd(&cur[d], 1);
  csr[pos] = s;
}

__global__ void csr_sort2(const int* __restrict__ offs0, int* __restrict__ csr0,
                          const int* __restrict__ offs1, int* __restrict__ csr1)
{
  int d = blockIdx.x * blockDim.x + threadIdx.x;
  if (d >= 2 * N_NODES) return;
  int type = d >= N_NODES;
  int i = type ? d - N_NODES : d;
  const int* offs = type ? offs1 : offs0;
  int* csr = type ? csr1 : csr0;
  int b = offs[i], e = offs[i + 1];
  for (int p = b + 1; p < e; p++) {
    int v = csr[p];
    int j = p - 1;
    while (j >= b && csr[j] > v) { csr[j + 1] = csr[j]; j--; }
    csr[j + 1] = v;
  }
}

// --------------------------------- all weight transposes/casts in one kernel
#define WSEG0 262144              // W0t   [256][1024]
#define WSEG1 (WSEG0 + 65536)     // W1t   [256][256]
#define WSEG2 (WSEG1 + 524288)    // WcatT [L][1024][256]
#define WSEG3 (WSEG2 + 262144)    // projcatT [L][256][512]
#define WSEG4 (WSEG3 + 65536)     // hW0t  [256][256]
#define WSEG5 (WSEG4 + 32768)     // hW1t  [128][256]
__global__ void wtrans_all(const float* __restrict__ pre_W0, const float* __restrict__ pre_W1,
                           const float* __restrict__ Wl, const float* __restrict__ Wr,
                           const float* __restrict__ proj_W,
                           const float* __restrict__ head_W0, const float* __restrict__ head_W1,
                           ushort* __restrict__ W0t, ushort* __restrict__ W1t,
                           ushort* __restrict__ WcatT, ushort* __restrict__ projcatT,
                           ushort* __restrict__ hW0t, ushort* __restrict__ hW1t)
{
  int i = blockIdx.x * blockDim.x + threadIdx.x;
  if (i < WSEG0) {
    int nrow = i >> 10, k = i & 1023;
    W0t[i] = f2bf(pre_W0[(size_t)k * 256 + nrow]);
  } else if (i < WSEG1) {
    int j = i - WSEG0;
    int nrow = j >> 8, k = j & 255;
    W1t[j] = f2bf(pre_W1[(size_t)k * 256 + nrow]);
  } else if (i < WSEG2) {
    int j = i - WSEG1;
    int l = j >> 18;
    int rem = j & 262143;
    int c = rem >> 8, k = rem & 255;
    int t = c >> 9, half = (c >> 8) & 1, cc = c & 255;
    const float* W = half ? Wr : Wl;
    WcatT[j] = f2bf(W[(((size_t)l * NTYPES + t) * 256 + k) * 256 + cc]);
  } else if (i < WSEG3) {
    int j = i - WSEG2;
    int l = j >> 17;
    int rem = j & 131071;
    int n = rem >> 9, k = rem & 511;
    int t = k >> 8, kk = k & 255;
    projcatT[j] = f2bf(proj_W[(((size_t)l * NTYPES + t) * 256 + kk) * 256 + n]);
  } else if (i < WSEG4) {
    int j = i - WSEG3;
    int nrow = j >> 8, k = j & 255;
    hW0t[j] = f2bf(head_W0[(size_t)k * 256 + nrow]);
  } else if (i < WSEG5) {
    int j = i - WSEG4;
    int nrow = j >> 8, k = j & 255;
    hW1t[j] = (nrow < OUT_DIM) ? f2bf(head_W1[(size_t)k * OUT_DIM + nrow]) : (ushort)0;
  }
}

// ---------------------------------------------- GATv2: dst-centric online SM
// grid = 2*ceil(N*64/256); first half type 0, second half type 1.
// out: [MP][512] bf16, type t writes cols [t*256, t*256+256)
__global__ void gat_edge2(const ushort* __restrict__ xlr,      // [MP,1024] bf16
                          const int* __restrict__ offs0, const int* __restrict__ csr0,
                          const int* __restrict__ offs1, const int* __restrict__ csr1,
                          const float* __restrict__ att,       // [2*256] layer base
                          const float* __restrict__ bias,      // [2*256] layer base
                          ushort* __restrict__ out, int nblk_per_type)
{
  int type = blockIdx.x >= nblk_per_type;
  int bid = type ? blockIdx.x - nblk_per_type : blockIdx.x;
  int wid = (bid * blockDim.x + threadIdx.x) >> 6;
  int lane = threadIdx.x & 63;
  if (wid >= N_NODES) return;
  const int* offs = type ? offs1 : offs0;
  const int* csr  = type ? csr1 : csr0;
  const int xl_col = type ? 512 : 0;
  const int xr_col = xl_col + 256;

  ushort4 xru = *reinterpret_cast<const ushort4*>(xlr + (size_t)wid * 1024 + xr_col + lane * 4);
  const float xr0 = bf2f(xru.x), xr1 = bf2f(xru.y), xr2 = bf2f(xru.z), xr3 = bf2f(xru.w);
  const float4 av = *reinterpret_cast<const float4*>(att + type * 256 + lane * 4);
  int beg = offs[wid], end = offs[wid + 1];

  float m = -INFINITY, den = 0.f;
  float a0 = 0.f, a1 = 0.f, a2 = 0.f, a3 = 0.f;

  for (int j = beg; j < end; j++) {
    int s = csr[j];
    ushort4 hsu = *reinterpret_cast<const ushort4*>(xlr + (size_t)s * 1024 + xl_col + lane * 4);
    float h0 = bf2f(hsu.x), h1 = bf2f(hsu.y), h2 = bf2f(hsu.z), h3 = bf2f(hsu.w);
    float e0 = h0 + xr0, e1 = h1 + xr1, e2 = h2 + xr2, e3 = h3 + xr3;
    e0 = e0 > 0.f ? e0 : 0.2f * e0;
    e1 = e1 > 0.f ? e1 : 0.2f * e1;
    e2 = e2 > 0.f ? e2 : 0.2f * e2;
    e3 = e3 > 0.f ? e3 : 0.2f * e3;
    float p = av.x * e0 + av.y * e1 + av.z * e2 + av.w * e3;
    p += __shfl_xor(p, 1);
    p += __shfl_xor(p, 2);
    p += __shfl_xor(p, 4);
    p += __shfl_xor(p, 8);
    float nm = fmaxf(m, p);
    float so = __expf(m - nm);
    float wgt = __expf(p - nm);
    den = den * so + wgt;
    a0 = a0 * so + wgt * h0;
    a1 = a1 * so + wgt * h1;
    a2 = a2 * so + wgt * h2;
    a3 = a3 * so + wgt * h3;
    m = nm;
  }
  float r = 1.f / (den + 1e-16f);
  const float4 b4 = *reinterpret_cast<const float4*>(bias + type * 256 + lane * 4);
  ushort4 o4;
  o4.x = f2bf(a0 * r + b4.x);
  o4.y = f2bf(a1 * r + b4.y);
  o4.z = f2bf(a2 * r + b4.z);
  o4.w = f2bf(a3 * r + b4.w);
  *reinterpret_cast<ushort4*>(out + (size_t)wid * 512 + type * 256 + lane * 4) = o4;
}

// ----------------------------------------------------------------- launcher
extern "C" void kernel_launch(void* const* d_in, const int* in_sizes, int n_in,
                              void* d_out, int out_size, void* d_ws, size_t ws_size,
                              hipStream_t stream)
{
  const float* x        = (const float*)d_in[0];
  const int*   ei0      = (const int*)d_in[1];
  const int*   ei1      = (const int*)d_in[2];
  const float* pre_W0   = (const float*)d_in[3];
  const float* pre_b0   = (const float*)d_in[4];
  const float* pre_g0   = (const float*)d_in[5];
  const float* pre_be0  = (const float*)d_in[6];
  const float* pre_W1   = (const float*)d_in[7];
  const float* pre_b1   = (const float*)d_in[8];
  const float* pre_g1   = (const float*)d_in[9];
  const float* pre_be1  = (const float*)d_in[10];
  const float* gat_Wl   = (const float*)d_in[11];
  const float* gat_Wr   = (const float*)d_in[12];
  const float* gat_att  = (const float*)d_in[13];
  const float* gat_bias = (const float*)d_in[14];
  const float* proj_W   = (const float*)d_in[15];
  const float* proj_b   = (const float*)d_in[16];
  const float* head_W0  = (const float*)d_in[17];
  const float* head_b0  = (const float*)d_in[18];
  const float* head_W1  = (const float*)d_in[19];
  const float* head_b1  = (const float*)d_in[20];
  float* outp = (float*)d_out;

  // ---- workspace arena (all segments 16B-aligned)
  char* ws = (char*)d_ws;
  ushort* xlr_b = (ushort*)ws; ws += (size_t)MP * 1024 * 2;
  ushort* hb    = (ushort*)ws; ws += (size_t)MP * 256 * 2;
  ushort* outt  = (ushort*)ws; ws += (size_t)MP * 512 * 2;   // gat concat out
  float*  tmp   = (float*)outt;                               // alias: pre-LN f32 buf
  ushort* hbuf  = (ushort*)outt;                              // alias: head0 out
  ushort* W0t      = (ushort*)ws; ws += (size_t)256 * 1024 * 2;
  ushort* W1t      = (ushort*)ws; ws += (size_t)256 * 256 * 2;
  ushort* WcatT    = (ushort*)ws; ws += (size_t)LAYERS * 1024 * 256 * 2;
  ushort* projcatT = (ushort*)ws; ws += (size_t)LAYERS * 256 * 512 * 2;
  ushort* hW0t     = (ushort*)ws; ws += (size_t)256 * 256 * 2;
  ushort* hW1t     = (ushort*)ws; ws += (size_t)128 * 256 * 2;
  int* cnt0  = (int*)ws; ws += (size_t)NPAD * 4;
  int* cnt1  = (int*)ws; ws += (size_t)NPAD * 4;
  int* offs0 = (int*)ws; ws += (size_t)(N_NODES + 4) * 4;
  int* offs1 = (int*)ws; ws += (size_t)(N_NODES + 4) * 4;
  int* cur0  = (int*)ws; ws += (size_t)N_NODES * 4;
  int* cur1  = (int*)ws; ws += (size_t)N_NODES * 4;
  int* bsums = (int*)ws; ws += (size_t)128 * 4;
  int* boffs = (int*)ws; ws += (size_t)128 * 4;
  int* csr0  = (int*)ws; ws += (size_t)EPRIME * 4;
  int* csr1  = (int*)ws; ws += (size_t)EPRIME * 4;

  // ---- CSR build (deterministic via per-bucket sort)
  hipMemsetAsync(cnt0, 0, (size_t)2 * NPAD * 4, stream);   // cnt0+cnt1 contiguous
  const int gE2 = (2 * EPRIME + 255) / 256;
  csr_count2<<<gE2, 256, 0, stream>>>(ei0, ei1, cnt0, cnt1);
  scan_p1<<<2 * SCAN_NBLK, 256, 0, stream>>>(cnt0, cnt1, bsums);
  scan_p2<<<1, 64, 0, stream>>>(bsums, boffs, offs0, offs1);
  scan_p3<<<2 * SCAN_NBLK, 256, 0, stream>>>(cnt0, cnt1, boffs, offs0, cur0, offs1, cur1);
  csr_scatter2<<<gE2, 256, 0, stream>>>(ei0, ei1, cur0, cur1, csr0, csr1);
  csr_sort2<<<(2 * N_NODES + 255) / 256, 256, 0, stream>>>(offs0, csr0, offs1, csr1);

  // ---- weights -> bf16 K-major (single launch)
  wtrans_all<<<WSEG5 / 256, 256, 0, stream>>>(pre_W0, pre_W1, gat_Wl, gat_Wr, proj_W,
                                              head_W0, head_W1,
                                              W0t, W1t, WcatT, projcatT, hW0t, hW1t);

  const dim3 blk(256);
  const int gy = MP / 128;   // 391
  const int gln = (N_NODES * 64 + 255) / 256;   // 12500

  // ---- preprocessor MLP (pre0 reads f32 x directly, casts in staging)
  gemm_k<true><<<dim3(2, gy), blk, 0, stream>>>(x, W0t, 1024, N_NODES, 256,
                                                tmp, nullptr, pre_b0, nullptr, 0);
  ln_relu<<<gln, 256, 0, stream>>>(tmp, hb, pre_g0, pre_be0, N_NODES);
  gemm_k<false><<<dim3(2, gy), blk, 0, stream>>>(hb, W1t, 256, N_NODES, 256,
                                                 tmp, nullptr, pre_b1, nullptr, 0);
  ln_relu<<<gln, 256, 0, stream>>>(tmp, hb, pre_g1, pre_be1, N_NODES);

  // ---- GNN layers
  for (int l = 0; l < LAYERS; l++) {
    gemm_k<false><<<dim3(8, gy), blk, 0, stream>>>(hb, WcatT + (size_t)l * 1024 * 256,
                                                   256, N_NODES, 1024,
                                                   nullptr, xlr_b, nullptr, nullptr, 0);
    gat_edge2<<<2 * gln, 256, 0, stream>>>(
        xlr_b, offs0, csr0, offs1, csr1,
        gat_att  + (size_t)l * NTYPES * NHEAD * DHEAD,
        gat_bias + (size_t)l * NTYPES * HID,
        outt, gln);
    gemm_k<false><<<dim3(2, gy), blk, 0, stream>>>(
        outt, projcatT + (size_t)l * 256 * 512, 512, N_NODES, 256,
        nullptr, hb,
        proj_b + (size_t)(l * NTYPES + 0) * HID,
        proj_b + (size_t)(l * NTYPES + 1) * HID, 1);
  }

  // ---- prediction head
  gemm_k<false><<<dim3(2, gy), blk, 0, stream>>>(hb, hW0t, 256, N_NODES, 256,
                                                 nullptr, hbuf, head_b0, nullptr, 1);
  gemm_k<false><<<dim3(1, gy), blk, 0, stream>>>(hbuf, hW1t, 256, N_NODES, OUT_DIM,
                                                 outp, nullptr, head_b1, nullptr, 0);
}

// Round 4
// 912.031 us; speedup vs baseline: 2.8225x; 1.1562x over previous
//
#include <hip/hip_runtime.h>
#include <hip/hip_bf16.h>
#include <math.h>

#define N_NODES 50000
#define MP      50048          // 391 * 128, padded row count
#define E_EDGES 500000
#define EPRIME  (E_EDGES + N_NODES)
#define HID     256
#define PRE_IN  1024
#define OUT_DIM 64
#define NHEAD   4
#define DHEAD   64
#define LAYERS  2
#define NTYPES  2

#define SCAN_NBLK 49                     // ceil(50000/1024)
#define NPAD      (SCAN_NBLK * 1024)     // 50176

typedef __attribute__((ext_vector_type(8))) short short8v;
typedef __attribute__((ext_vector_type(4))) float f32x4;
typedef _Float16 h2v __attribute__((ext_vector_type(2)));
typedef _Float16 h8v __attribute__((ext_vector_type(8)));

__device__ __forceinline__ ushort f2bf(float f) {
  uint u = __float_as_uint(f);
  u += 0x7FFF + ((u >> 16) & 1);          // RNE
  return (ushort)(u >> 16);
}
__device__ __forceinline__ float bf2f(ushort u) {
  return __uint_as_float(((uint)u) << 16);
}

// ------------------------------------------------------------- bf16 MFMA GEMM
// C[M,N] = op(A[M,K] @ Bt[N,K]^T + bias(+bias2) ); Bt bf16 K-major, rows padded.
// A: bf16 K-major (AF32=false) or f32 K-major (AF32=true, rows >= M read as 0).
// 128x128 tile, BK=32, 4 waves of 64x64, mfma_f32_16x16x32_bf16.
// LDS layout byte = row*64 + (kc ^ ((row>>1)&3))*16 (XOR swizzle on both sides).
template<bool AF32>
__global__ __launch_bounds__(256) void gemm_k(
    const void* __restrict__ Ap,
    const ushort* __restrict__ Bt,
    int K, int M, int N,
    float*  __restrict__ Cf,          // f32 out (or null)
    ushort* __restrict__ Cb,          // 16-bit out (or null)
    const float* __restrict__ bias,   // [N] or null
    const float* __restrict__ bias2,  // [N] or null (added too)
    int do_relu, int out_f16)         // out_f16: Cb holds fp16 instead of bf16
{
  __shared__ ushort As[128 * 32];
  __shared__ ushort Bs[128 * 32];
  const int tid = threadIdx.x;
  const int l   = tid & 63;
  const int w   = tid >> 6;
  const int wm  = w & 1;
  const int wn  = w >> 1;
  const int bm  = blockIdx.y * 128;
  const int bn  = blockIdx.x * 128;

  f32x4 acc[4][4];
#pragma unroll
  for (int m = 0; m < 4; m++)
#pragma unroll
    for (int n = 0; n < 4; n++) acc[m][n] = (f32x4){0.f, 0.f, 0.f, 0.f};

  const int srow  = l >> 2;   // 0..15
  const int sslot = l & 3;    // kc slot

  for (int k0 = 0; k0 < K; k0 += 32) {
#pragma unroll
    for (int i = 0; i < 2; i++) {
      const int row = w * 32 + i * 16 + srow;
      const int kc  = sslot ^ ((row >> 1) & 3);     // inverse-swizzled source
      const uint off = (uint)row * 64 + (uint)sslot * 16;  // wave base + l*16
      const ushort* gb = Bt + (size_t)(bn + row) * K + k0 + kc * 8;
      __builtin_amdgcn_global_load_lds(
          (const __attribute__((address_space(1))) uint*)gb,
          (__attribute__((address_space(3))) uint*)((char*)Bs + off), 16, 0, 0);
      if constexpr (AF32) {
        const float* ga = (const float*)Ap + (size_t)(bm + row) * K + k0 + kc * 8;
        float4 v0 = make_float4(0.f, 0.f, 0.f, 0.f);
        float4 v1 = make_float4(0.f, 0.f, 0.f, 0.f);
        if (bm + row < M) {
          v0 = *reinterpret_cast<const float4*>(ga);
          v1 = *reinterpret_cast<const float4*>(ga + 4);
        }
        short8v s;
        s[0] = (short)f2bf(v0.x); s[1] = (short)f2bf(v0.y);
        s[2] = (short)f2bf(v0.z); s[3] = (short)f2bf(v0.w);
        s[4] = (short)f2bf(v1.x); s[5] = (short)f2bf(v1.y);
        s[6] = (short)f2bf(v1.z); s[7] = (short)f2bf(v1.w);
        *reinterpret_cast<short8v*>((char*)As + off) = s;
      } else {
        const ushort* ga = (const ushort*)Ap + (size_t)(bm + row) * K + k0 + kc * 8;
        __builtin_amdgcn_global_load_lds(
            (const __attribute__((address_space(1))) uint*)ga,
            (__attribute__((address_space(3))) uint*)((char*)As + off), 16, 0, 0);
      }
    }
    __syncthreads();

    short8v a[4], b[4];
#pragma unroll
    for (int m = 0; m < 4; m++) {
      const int row = wm * 64 + m * 16 + (l & 15);
      const int kc  = (l >> 4) ^ ((row >> 1) & 3);
      a[m] = *(const short8v*)((const char*)As + row * 64 + kc * 16);
    }
#pragma unroll
    for (int n = 0; n < 4; n++) {
      const int row = wn * 64 + n * 16 + (l & 15);
      const int kc  = (l >> 4) ^ ((row >> 1) & 3);
      b[n] = *(const short8v*)((const char*)Bs + row * 64 + kc * 16);
    }
#pragma unroll
    for (int m = 0; m < 4; m++)
#pragma unroll
      for (int n = 0; n < 4; n++)
        acc[m][n] = __builtin_amdgcn_mfma_f32_16x16x32_bf16(a[m], b[n], acc[m][n], 0, 0, 0);
    __syncthreads();
  }

  // epilogue: C/D map col=lane&15, row=(lane>>4)*4+reg
  const int crow0 = bm + wm * 64 + (l >> 4) * 4;
  const int ccol0 = bn + wn * 64 + (l & 15);
#pragma unroll
  for (int m = 0; m < 4; m++) {
#pragma unroll
    for (int j = 0; j < 4; j++) {
      const int grow = crow0 + m * 16 + j;
      if (grow < M) {
#pragma unroll
        for (int n = 0; n < 4; n++) {
          const int gcol = ccol0 + n * 16;
          if (gcol < N) {
            float v = acc[m][n][j];
            if (bias)  v += bias[gcol];
            if (bias2) v += bias2[gcol];
            if (do_relu) v = fmaxf(v, 0.f);
            if (Cf) Cf[(size_t)grow * N + gcol] = v;
            else if (out_f16) {
              _Float16 hv = (_Float16)v;
              Cb[(size_t)grow * N + gcol] = *(ushort*)&hv;
            } else {
              Cb[(size_t)grow * N + gcol] = f2bf(v);
            }
          }
        }
      }
    }
  }
}

// ------------------------------------------------------------ LayerNorm+ReLU
__global__ void ln_relu(const float* __restrict__ in, ushort* __restrict__ out,
                        const float* __restrict__ g, const float* __restrict__ be, int n)
{
  int gid = blockIdx.x * blockDim.x + threadIdx.x;
  int row = gid >> 6;
  int lane = threadIdx.x & 63;
  if (row >= n) return;
  float4 v = *reinterpret_cast<const float4*>(in + (size_t)row * HID + lane * 4);
  float s = v.x + v.y + v.z + v.w;
  float ss = v.x * v.x + v.y * v.y + v.z * v.z + v.w * v.w;
#pragma unroll
  for (int o = 1; o < 64; o <<= 1) { s += __shfl_xor(s, o); ss += __shfl_xor(ss, o); }
  float mu = s * (1.f / 256.f);
  float var = ss * (1.f / 256.f) - mu * mu;
  float inv = rsqrtf(var + 1e-5f);
  float4 gg = *reinterpret_cast<const float4*>(g + lane * 4);
  float4 bb = *reinterpret_cast<const float4*>(be + lane * 4);
  ushort4 o4;
  o4.x = f2bf(fmaxf((v.x - mu) * inv * gg.x + bb.x, 0.f));
  o4.y = f2bf(fmaxf((v.y - mu) * inv * gg.y + bb.y, 0.f));
  o4.z = f2bf(fmaxf((v.z - mu) * inv * gg.z + bb.z, 0.f));
  o4.w = f2bf(fmaxf((v.w - mu) * inv * gg.w + bb.w, 0.f));
  *reinterpret_cast<ushort4*>(out + (size_t)row * HID + lane * 4) = o4;
}

// ------------------------------------------------------------- CSR building
__global__ void csr_count2(const int* __restrict__ ei0, const int* __restrict__ ei1,
                           int* __restrict__ cnt0, int* __restrict__ cnt1)
{
  int e = blockIdx.x * blockDim.x + threadIdx.x;
  if (e >= 2 * EPRIME) return;
  int type = e >= EPRIME;
  int i = type ? e - EPRIME : e;
  const int* ei = type ? ei1 : ei0;
  int* cnt = type ? cnt1 : cnt0;
  int d = (i < E_EDGES) ? ei[E_EDGES + i] : (i - E_EDGES);
  atomicAdd(&cnt[d], 1);
}

// --- hierarchical exclusive scan over cnt0,cnt1 (padded to NPAD with zeros)
__global__ __launch_bounds__(256) void scan_p1(const int* __restrict__ cnt0,
                                               const int* __restrict__ cnt1,
                                               int* __restrict__ bsums)
{
  int type = blockIdx.x >= SCAN_NBLK;
  int blk = type ? blockIdx.x - SCAN_NBLK : blockIdx.x;
  const int* cnt = type ? cnt1 : cnt0;
  int4 v = reinterpret_cast<const int4*>(cnt)[blk * 256 + threadIdx.x];
  int s = v.x + v.y + v.z + v.w;
#pragma unroll
  for (int o = 1; o < 64; o <<= 1) s += __shfl_xor(s, o);
  __shared__ int wt[4];
  if ((threadIdx.x & 63) == 0) wt[threadIdx.x >> 6] = s;
  __syncthreads();
  if (threadIdx.x == 0) bsums[blockIdx.x] = wt[0] + wt[1] + wt[2] + wt[3];
}

__global__ void scan_p2(const int* __restrict__ bsums, int* __restrict__ boffs,
                        int* __restrict__ offs0, int* __restrict__ offs1)
{
  int t = threadIdx.x;
  if (t < 2) {
    int run = 0;
    for (int i = 0; i < SCAN_NBLK; i++) {
      boffs[t * SCAN_NBLK + i] = run;
      run += bsums[t * SCAN_NBLK + i];
    }
  }
  if (t == 2) offs0[N_NODES] = EPRIME;
  if (t == 3) offs1[N_NODES] = EPRIME;
}

__global__ __launch_bounds__(256) void scan_p3(
    const int* __restrict__ cnt0, const int* __restrict__ cnt1,
    const int* __restrict__ boffs,
    int* __restrict__ offs0, int* __restrict__ cur0,
    int* __restrict__ offs1, int* __restrict__ cur1)
{
  int type = blockIdx.x >= SCAN_NBLK;
  int blk = type ? blockIdx.x - SCAN_NBLK : blockIdx.x;
  const int* cnt = type ? cnt1 : cnt0;
  int* offs = type ? offs1 : offs0;
  int* cur  = type ? cur1 : cur0;
  const int tid = threadIdx.x, lane = tid & 63, wv = tid >> 6;
  int4 v = reinterpret_cast<const int4*>(cnt)[blk * 256 + tid];
  int e1 = v.x, e2 = e1 + v.y, e3 = e2 + v.z, T = e3 + v.w;
  int incl = T;
#pragma unroll
  for (int o = 1; o < 64; o <<= 1) {
    int nb = __shfl_up(incl, o);
    if (lane >= o) incl += nb;
  }
  __shared__ int wt[4];
  if (lane == 63) wt[wv] = incl;
  __syncthreads();
  int wexcl = 0;
  for (int i = 0; i < wv; i++) wexcl += wt[i];
  int base = boffs[blockIdx.x] + wexcl + (incl - T);
  int idx = blk * 1024 + tid * 4;
  int4 o4 = make_int4(base, base + e1, base + e2, base + e3);
  if (idx + 3 < N_NODES) {
    reinterpret_cast<int4*>(offs)[idx >> 2] = o4;
    reinterpret_cast<int4*>(cur)[idx >> 2] = o4;
  } else {
    if (idx + 0 < N_NODES) { offs[idx + 0] = o4.x; cur[idx + 0] = o4.x; }
    if (idx + 1 < N_NODES) { offs[idx + 1] = o4.y; cur[idx + 1] = o4.y; }
    if (idx + 2 < N_NODES) { offs[idx + 2] = o4.z; cur[idx + 2] = o4.z; }
    if (idx + 3 < N_NODES) { offs[idx + 3] = o4.w; cur[idx + 3] = o4.w; }
  }
}

__global__ void csr_scatter2(const int* __restrict__ ei0, const int* __restrict__ ei1,
                             int* __restrict__ cur0, int* __restrict__ cur1,
                             int* __restrict__ csr0, int* __restrict__ csr1)
{
  int e = blockIdx.x * blockDim.x + threadIdx.x;
  if (e >= 2 * EPRIME) return;
  int type = e >= EPRIME;
  int i = type ? e - EPRIME : e;
  const int* ei = type ? ei1 : ei0;
  int* cur = type ? cur1 : cur0;
  int* csr = type ? csr1 : csr0;
  int d = (i < E_EDGES) ? ei[E_EDGES + i] : (i - E_EDGES);
  int s = (i < E_EDGES) ? ei[i] : (i - E_EDGES);
  int pos = atomicAdd(&cur[d], 1);
  csr[pos] = s;
}

__global__ void csr_sort2(const int* __restrict__ offs0, int* __restrict__ csr0,
                          const int* __restrict__ offs1, int* __restrict__ csr1)
{
  int d = blockIdx.x * blockDim.x + threadIdx.x;
  if (d >= 2 * N_NODES) return;
  int type = d >= N_NODES;
  int i = type ? d - N_NODES : d;
  const int* offs = type ? offs1 : offs0;
  int* csr = type ? csr1 : csr0;
  int b = offs[i], e = offs[i + 1];
  for (int p = b + 1; p < e; p++) {
    int v = csr[p];
    int j = p - 1;
    while (j >= b && csr[j] > v) { csr[j + 1] = csr[j]; j--; }
    csr[j + 1] = v;
  }
}

// --------------------------------- all weight transposes/casts in one kernel
#define WSEG0 262144              // W0t   [256][1024]
#define WSEG1 (WSEG0 + 65536)     // W1t   [256][256]
#define WSEG2 (WSEG1 + 524288)    // WcatT [L][1024][256]
#define WSEG3 (WSEG2 + 262144)    // projcatT [L][256][512]
#define WSEG4 (WSEG3 + 65536)     // hW0t  [256][256]
#define WSEG5 (WSEG4 + 32768)     // hW1t  [128][256]
__global__ void wtrans_all(const float* __restrict__ pre_W0, const float* __restrict__ pre_W1,
                           const float* __restrict__ Wl, const float* __restrict__ Wr,
                           const float* __restrict__ proj_W,
                           const float* __restrict__ head_W0, const float* __restrict__ head_W1,
                           ushort* __restrict__ W0t, ushort* __restrict__ W1t,
                           ushort* __restrict__ WcatT, ushort* __restrict__ projcatT,
                           ushort* __restrict__ hW0t, ushort* __restrict__ hW1t)
{
  int i = blockIdx.x * blockDim.x + threadIdx.x;
  if (i < WSEG0) {
    int nrow = i >> 10, k = i & 1023;
    W0t[i] = f2bf(pre_W0[(size_t)k * 256 + nrow]);
  } else if (i < WSEG1) {
    int j = i - WSEG0;
    int nrow = j >> 8, k = j & 255;
    W1t[j] = f2bf(pre_W1[(size_t)k * 256 + nrow]);
  } else if (i < WSEG2) {
    int j = i - WSEG1;
    int l = j >> 18;
    int rem = j & 262143;
    int c = rem >> 8, k = rem & 255;
    int t = c >> 9, half = (c >> 8) & 1, cc = c & 255;
    const float* W = half ? Wr : Wl;
    WcatT[j] = f2bf(W[(((size_t)l * NTYPES + t) * 256 + k) * 256 + cc]);
  } else if (i < WSEG3) {
    int j = i - WSEG2;
    int l = j >> 17;
    int rem = j & 131071;
    int n = rem >> 9, k = rem & 511;
    int t = k >> 8, kk = k & 255;
    projcatT[j] = f2bf(proj_W[(((size_t)l * NTYPES + t) * 256 + kk) * 256 + n]);
  } else if (i < WSEG4) {
    int j = i - WSEG3;
    int nrow = j >> 8, k = j & 255;
    hW0t[j] = f2bf(head_W0[(size_t)k * 256 + nrow]);
  } else if (i < WSEG5) {
    int j = i - WSEG4;
    int nrow = j >> 8, k = j & 255;
    hW1t[j] = (nrow < OUT_DIM) ? f2bf(head_W1[(size_t)k * OUT_DIM + nrow]) : (ushort)0;
  }
}

// --------------------------------------------------------- DPP 8-lane reduce
__device__ __forceinline__ float dpp8_sum(float p) {
  // sum over lanes (l & ~7)..(l | 7): xor1, xor2 (quad_perm), then half-mirror
  p += __int_as_float(__builtin_amdgcn_update_dpp(0, __float_as_int(p), 0xB1, 0xF, 0xF, true));
  p += __int_as_float(__builtin_amdgcn_update_dpp(0, __float_as_int(p), 0x4E, 0xF, 0xF, true));
  p += __int_as_float(__builtin_amdgcn_update_dpp(0, __float_as_int(p), 0x141, 0xF, 0xF, true));
  return p;
}

__device__ __forceinline__ h8v leaky8(h8v x) {
  const _Float16 c = (_Float16)0.2f;
  h8v y = x * c;
#if __has_builtin(__builtin_elementwise_max)
  return __builtin_elementwise_max(x, y);
#else
  h8v r;
#pragma unroll
  for (int i = 0; i < 8; i++) r[i] = x[i] > y[i] ? x[i] : y[i];
  return r;
#endif
}

__device__ __forceinline__ float dot8(h8v e, const h2v* a) {
  h2v e0 = {e[0], e[1]}, e1 = {e[2], e[3]}, e2 = {e[4], e[5]}, e3 = {e[6], e[7]};
#if __has_builtin(__builtin_amdgcn_fdot2)
  float s = __builtin_amdgcn_fdot2(e0, a[0], 0.f, false);
  s = __builtin_amdgcn_fdot2(e1, a[1], s, false);
  s = __builtin_amdgcn_fdot2(e2, a[2], s, false);
  s = __builtin_amdgcn_fdot2(e3, a[3], s, false);
  return s;
#else
  float s = 0.f;
#pragma unroll
  for (int i = 0; i < 8; i++) s += (float)e[i] * (float)a[i >> 1][i & 1];
  return s;
#endif
}

// ---------------------------------------------- GATv2: dst-centric online SM
// one wave per dst; lanes 0-31 = even edges, 32-63 = odd; 4 edges in flight.
// lane li owns 8 channels (16 B fp16); head = li>>3; DPP reduce over 8 lanes.
__global__ __launch_bounds__(256) void gat_edge3(
    const _Float16* __restrict__ xlr,   // [MP,1024] fp16
    const int* __restrict__ offs0, const int* __restrict__ csr0,
    const int* __restrict__ offs1, const int* __restrict__ csr1,
    const float* __restrict__ att,      // [2*256] layer base
    const float* __restrict__ bias,     // [2*256] layer base
    ushort* __restrict__ out, int nblk_per_type)
{
  const int type = blockIdx.x >= nblk_per_type;
  const int bid = type ? blockIdx.x - nblk_per_type : blockIdx.x;
  const int wid = (bid * 256 + threadIdx.x) >> 6;
  if (wid >= N_NODES) return;
  const int lane = threadIdx.x & 63;
  const int half = lane >> 5, li = lane & 31;
  const int* offs = type ? offs1 : offs0;
  const int* csr  = type ? csr1 : csr0;
  const int xl_col = type ? 512 : 0;

  // att (8 ch/lane) -> packed fp16 pairs
  const float* ap = att + type * 256 + li * 8;
  h2v a[4];
#pragma unroll
  for (int i = 0; i < 4; i++) {
    a[i][0] = (_Float16)ap[2 * i];
    a[i][1] = (_Float16)ap[2 * i + 1];
  }
  const h8v xr = *reinterpret_cast<const h8v*>(xlr + (size_t)wid * 1024 + xl_col + 256 + li * 8);

  const int beg = offs[wid], end = offs[wid + 1];
  const float L2E = 1.44269504f;
  float m = -1e30f, den = 0.f;
  float acc[8];
#pragma unroll
  for (int i = 0; i < 8; i++) acc[i] = 0.f;

  const int ng = (end - beg + 3) >> 2;
  for (int g = 0; g < ng; g++) {
    const int j0 = beg + 4 * g + half;
    const int j1 = j0 + 2;
    const bool v0 = j0 < end, v1 = j1 < end;
    const int s0 = csr[v0 ? j0 : beg];
    const int s1 = csr[v1 ? j1 : beg];
    const h8v hs0 = *reinterpret_cast<const h8v*>(xlr + (size_t)s0 * 1024 + xl_col + li * 8);
    const h8v hs1 = *reinterpret_cast<const h8v*>(xlr + (size_t)s1 * 1024 + xl_col + li * 8);
    float p0 = dpp8_sum(dot8(leaky8(hs0 + xr), a));
    float p1 = dpp8_sum(dot8(leaky8(hs1 + xr), a));
    if (!v0) p0 = -INFINITY;
    if (!v1) p1 = -INFINITY;
    const float pm = fmaxf(p0, p1);
    if (__any(pm > m + 4.f)) {           // defer-max rescale (rare)
      const float nm = fmaxf(m, pm);
      const float so = exp2f((m - nm) * L2E);
      den *= so;
#pragma unroll
      for (int i = 0; i < 8; i++) acc[i] *= so;
      m = nm;
    }
    const float w0 = exp2f((p0 - m) * L2E);
    const float w1 = exp2f((p1 - m) * L2E);
    den += w0 + w1;
#pragma unroll
    for (int i = 0; i < 8; i++) {
      acc[i] = fmaf((float)hs0[i], w0, acc[i]);
      acc[i] = fmaf((float)hs1[i], w1, acc[i]);
    }
  }

  // merge the two halves
  const float mo  = __shfl_xor(m, 32);
  const float dno = __shfl_xor(den, 32);
  const float ms = fmaxf(m, mo);
  const float fa = exp2f((m - ms) * L2E);
  const float fb = exp2f((mo - ms) * L2E);
  const float r = 1.f / (den * fa + dno * fb + 1e-16f);
  float of[8];
#pragma unroll
  for (int i = 0; i < 8; i++)
    of[i] = (acc[i] * fa + __shfl_xor(acc[i], 32) * fb) * r;

  if (half == 0) {
    const float* bp = bias + type * 256 + li * 8;
    uint4 o;
    uint pk[4];
#pragma unroll
    for (int i = 0; i < 4; i++) {
      const uint lo = f2bf(of[2 * i] + bp[2 * i]);
      const uint hi = f2bf(of[2 * i + 1] + bp[2 * i + 1]);
      pk[i] = lo | (hi << 16);
    }
    o.x = pk[0]; o.y = pk[1]; o.z = pk[2]; o.w = pk[3];
    *reinterpret_cast<uint4*>(out + (size_t)wid * 512 + type * 256 + li * 8) = o;
  }
}

// ----------------------------------------------------------------- launcher
extern "C" void kernel_launch(void* const* d_in, const int* in_sizes, int n_in,
                              void* d_out, int out_size, void* d_ws, size_t ws_size,
                              hipStream_t stream)
{
  const float* x        = (const float*)d_in[0];
  const int*   ei0      = (const int*)d_in[1];
  const int*   ei1      = (const int*)d_in[2];
  const float* pre_W0   = (const float*)d_in[3];
  const float* pre_b0   = (const float*)d_in[4];
  const float* pre_g0   = (const float*)d_in[5];
  const float* pre_be0  = (const float*)d_in[6];
  const float* pre_W1   = (const float*)d_in[7];
  const float* pre_b1   = (const float*)d_in[8];
  const float* pre_g1   = (const float*)d_in[9];
  const float* pre_be1  = (const float*)d_in[10];
  const float* gat_Wl   = (const float*)d_in[11];
  const float* gat_Wr   = (const float*)d_in[12];
  const float* gat_att  = (const float*)d_in[13];
  const float* gat_bias = (const float*)d_in[14];
  const float* proj_W   = (const float*)d_in[15];
  const float* proj_b   = (const float*)d_in[16];
  const float* head_W0  = (const float*)d_in[17];
  const float* head_b0  = (const float*)d_in[18];
  const float* head_W1  = (const float*)d_in[19];
  const float* head_b1  = (const float*)d_in[20];
  float* outp = (float*)d_out;

  // ---- workspace arena (all segments 16B-aligned)
  char* ws = (char*)d_ws;
  ushort* xlr_b = (ushort*)ws; ws += (size_t)MP * 1024 * 2;   // fp16 GAT input
  ushort* hb    = (ushort*)ws; ws += (size_t)MP * 256 * 2;
  ushort* outt  = (ushort*)ws; ws += (size_t)MP * 512 * 2;   // gat concat out
  float*  tmp   = (float*)outt;                               // alias: pre-LN f32 buf
  ushort* hbuf  = (ushort*)outt;                              // alias: head0 out
  ushort* W0t      = (ushort*)ws; ws += (size_t)256 * 1024 * 2;
  ushort* W1t      = (ushort*)ws; ws += (size_t)256 * 256 * 2;
  ushort* WcatT    = (ushort*)ws; ws += (size_t)LAYERS * 1024 * 256 * 2;
  ushort* projcatT = (ushort*)ws; ws += (size_t)LAYERS * 256 * 512 * 2;
  ushort* hW0t     = (ushort*)ws; ws += (size_t)256 * 256 * 2;
  ushort* hW1t     = (ushort*)ws; ws += (size_t)128 * 256 * 2;
  int* cnt0  = (int*)ws; ws += (size_t)NPAD * 4;
  int* cnt1  = (int*)ws; ws += (size_t)NPAD * 4;
  int* offs0 = (int*)ws; ws += (size_t)(N_NODES + 4) * 4;
  int* offs1 = (int*)ws; ws += (size_t)(N_NODES + 4) * 4;
  int* cur0  = (int*)ws; ws += (size_t)N_NODES * 4;
  int* cur1  = (int*)ws; ws += (size_t)N_NODES * 4;
  int* bsums = (int*)ws; ws += (size_t)128 * 4;
  int* boffs = (int*)ws; ws += (size_t)128 * 4;
  int* csr0  = (int*)ws; ws += (size_t)EPRIME * 4;
  int* csr1  = (int*)ws; ws += (size_t)EPRIME * 4;

  // ---- CSR build (deterministic via per-bucket sort)
  hipMemsetAsync(cnt0, 0, (size_t)2 * NPAD * 4, stream);   // cnt0+cnt1 contiguous
  const int gE2 = (2 * EPRIME + 255) / 256;
  csr_count2<<<gE2, 256, 0, stream>>>(ei0, ei1, cnt0, cnt1);
  scan_p1<<<2 * SCAN_NBLK, 256, 0, stream>>>(cnt0, cnt1, bsums);
  scan_p2<<<1, 64, 0, stream>>>(bsums, boffs, offs0, offs1);
  scan_p3<<<2 * SCAN_NBLK, 256, 0, stream>>>(cnt0, cnt1, boffs, offs0, cur0, offs1, cur1);
  csr_scatter2<<<gE2, 256, 0, stream>>>(ei0, ei1, cur0, cur1, csr0, csr1);
  csr_sort2<<<(2 * N_NODES + 255) / 256, 256, 0, stream>>>(offs0, csr0, offs1, csr1);

  // ---- weights -> bf16 K-major (single launch)
  wtrans_all<<<WSEG5 / 256, 256, 0, stream>>>(pre_W0, pre_W1, gat_Wl, gat_Wr, proj_W,
                                              head_W0, head_W1,
                                              W0t, W1t, WcatT, projcatT, hW0t, hW1t);

  const dim3 blk(256);
  const int gy = MP / 128;   // 391
  const int gln = (N_NODES * 64 + 255) / 256;   // 12500

  // ---- preprocessor MLP (pre0 reads f32 x directly, casts in staging)
  gemm_k<true><<<dim3(2, gy), blk, 0, stream>>>(x, W0t, 1024, N_NODES, 256,
                                                tmp, nullptr, pre_b0, nullptr, 0, 0);
  ln_relu<<<gln, 256, 0, stream>>>(tmp, hb, pre_g0, pre_be0, N_NODES);
  gemm_k<false><<<dim3(2, gy), blk, 0, stream>>>(hb, W1t, 256, N_NODES, 256,
                                                 tmp, nullptr, pre_b1, nullptr, 0, 0);
  ln_relu<<<gln, 256, 0, stream>>>(tmp, hb, pre_g1, pre_be1, N_NODES);

  // ---- GNN layers
  for (int l = 0; l < LAYERS; l++) {
    gemm_k<false><<<dim3(8, gy), blk, 0, stream>>>(hb, WcatT + (size_t)l * 1024 * 256,
                                                   256, N_NODES, 1024,
                                                   nullptr, xlr_b, nullptr, nullptr, 0, 1);
    gat_edge3<<<2 * gln, 256, 0, stream>>>(
        (const _Float16*)xlr_b, offs0, csr0, offs1, csr1,
        gat_att  + (size_t)l * NTYPES * NHEAD * DHEAD,
        gat_bias + (size_t)l * NTYPES * HID,
        outt, gln);
    gemm_k<false><<<dim3(2, gy), blk, 0, stream>>>(
        outt, projcatT + (size_t)l * 256 * 512, 512, N_NODES, 256,
        nullptr, hb,
        proj_b + (size_t)(l * NTYPES + 0) * HID,
        proj_b + (size_t)(l * NTYPES + 1) * HID, 1, 0);
  }

  // ---- prediction head
  gemm_k<false><<<dim3(2, gy), blk, 0, stream>>>(hb, hW0t, 256, N_NODES, 256,
                                                 nullptr, hbuf, head_b0, nullptr, 1, 0);
  gemm_k<false><<<dim3(1, gy), blk, 0, stream>>>(hbuf, hW1t, 256, N_NODES, OUT_DIM,
                                                 outp, nullptr, head_b1, nullptr, 0, 0);
}

// Round 5
// 868.871 us; speedup vs baseline: 2.9627x; 1.0497x over previous
//
#include <hip/hip_runtime.h>
#include <hip/hip_bf16.h>
#include <math.h>

#define N_NODES 50000
#define MP      50048          // 391 * 128, padded row count
#define E_EDGES 500000
#define EPRIME  (E_EDGES + N_NODES)
#define HID     256
#define PRE_IN  1024
#define OUT_DIM 64
#define NHEAD   4
#define DHEAD   64
#define LAYERS  2
#define NTYPES  2

#define SCAN_NBLK 49                     // ceil(50000/1024)
#define NPAD      (SCAN_NBLK * 1024)     // 50176

typedef __attribute__((ext_vector_type(8))) short short8v;
typedef __attribute__((ext_vector_type(4))) float f32x4;
typedef _Float16 h2v __attribute__((ext_vector_type(2)));
typedef _Float16 h8v __attribute__((ext_vector_type(8)));

__device__ __forceinline__ ushort f2bf(float f) {
  uint u = __float_as_uint(f);
  u += 0x7FFF + ((u >> 16) & 1);          // RNE
  return (ushort)(u >> 16);
}
__device__ __forceinline__ float bf2f(ushort u) {
  return __uint_as_float(((uint)u) << 16);
}

// ------------------------------------------------------------- bf16 MFMA GEMM
// C[M,N] = op(A[M,K] @ Bt[N,K]^T + bias(+bias2)); Bt bf16 K-major, rows padded.
// A: bf16 K-major (AF32=false) or f32 K-major (AF32=true, rows >= M read as 0).
// BM=128, BN=64, BK=32; 4 waves, wave-tile 64x32 (acc[4][2], 8 MFMA/K-step).
// Grid = (ceil(N/64), MP/128) -> 2x the blocks of the old 128x128 tiling:
// N=256 GEMMs get ~6 blocks/CU (was 3) -- occupancy was the Round-4 limiter.
// LDS layout byte = row*64 + (kc ^ ((row>>1)&3))*16 (XOR swizzle on both sides).
template<bool AF32>
__global__ __launch_bounds__(256) void gemm_k(
    const void* __restrict__ Ap,
    const ushort* __restrict__ Bt,
    int K, int M, int N,
    float*  __restrict__ Cf,          // f32 out (or null)
    ushort* __restrict__ Cb,          // 16-bit out (or null)
    const float* __restrict__ bias,   // [N] or null
    const float* __restrict__ bias2,  // [N] or null (added too)
    int do_relu, int out_f16)         // out_f16: Cb holds fp16 instead of bf16
{
  __shared__ ushort As[128 * 32];     // 8 KB
  __shared__ ushort Bs[64 * 32];      // 4 KB
  const int tid = threadIdx.x;
  const int l   = tid & 63;
  const int w   = tid >> 6;
  const int wm  = w & 1;              // row half (64 rows)
  const int wn  = w >> 1;             // col quarter (32 cols)
  const int bm  = blockIdx.y * 128;
  const int bn  = blockIdx.x * 64;

  f32x4 acc[4][2];
#pragma unroll
  for (int m = 0; m < 4; m++)
#pragma unroll
    for (int n = 0; n < 2; n++) acc[m][n] = (f32x4){0.f, 0.f, 0.f, 0.f};

  const int srow  = l >> 2;   // 0..15
  const int sslot = l & 3;    // kc slot

  // B staging geometry: one 16B slot per thread, dest = tid*16 (wave-linear)
  const int brow  = tid >> 2;        // 0..63
  const int bslot = tid & 3;
  const int bkc   = bslot ^ ((brow >> 1) & 3);

  for (int k0 = 0; k0 < K; k0 += 32) {
    // ---- stage B tile 64x32
    {
      const ushort* gb = Bt + (size_t)(bn + brow) * K + k0 + bkc * 8;
      __builtin_amdgcn_global_load_lds(
          (const __attribute__((address_space(1))) uint*)gb,
          (__attribute__((address_space(3))) uint*)((char*)Bs + tid * 16), 16, 0, 0);
    }
    // ---- stage A tile 128x32: wave w covers rows [w*32, w*32+32)
#pragma unroll
    for (int i = 0; i < 2; i++) {
      const int row = w * 32 + i * 16 + srow;
      const int kc  = sslot ^ ((row >> 1) & 3);     // inverse-swizzled source
      const uint off = (uint)row * 64 + (uint)sslot * 16;
      if constexpr (AF32) {
        const float* ga = (const float*)Ap + (size_t)(bm + row) * K + k0 + kc * 8;
        float4 v0 = make_float4(0.f, 0.f, 0.f, 0.f);
        float4 v1 = make_float4(0.f, 0.f, 0.f, 0.f);
        if (bm + row < M) {
          v0 = *reinterpret_cast<const float4*>(ga);
          v1 = *reinterpret_cast<const float4*>(ga + 4);
        }
        short8v s;
        s[0] = (short)f2bf(v0.x); s[1] = (short)f2bf(v0.y);
        s[2] = (short)f2bf(v0.z); s[3] = (short)f2bf(v0.w);
        s[4] = (short)f2bf(v1.x); s[5] = (short)f2bf(v1.y);
        s[6] = (short)f2bf(v1.z); s[7] = (short)f2bf(v1.w);
        *reinterpret_cast<short8v*>((char*)As + off) = s;
      } else {
        const ushort* ga = (const ushort*)Ap + (size_t)(bm + row) * K + k0 + kc * 8;
        __builtin_amdgcn_global_load_lds(
            (const __attribute__((address_space(1))) uint*)ga,
            (__attribute__((address_space(3))) uint*)((char*)As + off), 16, 0, 0);
      }
    }
    __syncthreads();

    short8v a[4], b[2];
#pragma unroll
    for (int m = 0; m < 4; m++) {
      const int row = wm * 64 + m * 16 + (l & 15);
      const int kc  = (l >> 4) ^ ((row >> 1) & 3);
      a[m] = *(const short8v*)((const char*)As + row * 64 + kc * 16);
    }
#pragma unroll
    for (int n = 0; n < 2; n++) {
      const int row = wn * 32 + n * 16 + (l & 15);
      const int kc  = (l >> 4) ^ ((row >> 1) & 3);
      b[n] = *(const short8v*)((const char*)Bs + row * 64 + kc * 16);
    }
#pragma unroll
    for (int m = 0; m < 4; m++)
#pragma unroll
      for (int n = 0; n < 2; n++)
        acc[m][n] = __builtin_amdgcn_mfma_f32_16x16x32_bf16(a[m], b[n], acc[m][n], 0, 0, 0);
    __syncthreads();
  }

  // epilogue: C/D map col=lane&15, row=(lane>>4)*4+reg
  const int crow0 = bm + wm * 64 + (l >> 4) * 4;
  const int ccol0 = bn + wn * 32 + (l & 15);
#pragma unroll
  for (int m = 0; m < 4; m++) {
#pragma unroll
    for (int j = 0; j < 4; j++) {
      const int grow = crow0 + m * 16 + j;
      if (grow < M) {
#pragma unroll
        for (int n = 0; n < 2; n++) {
          const int gcol = ccol0 + n * 16;
          if (gcol < N) {
            float v = acc[m][n][j];
            if (bias)  v += bias[gcol];
            if (bias2) v += bias2[gcol];
            if (do_relu) v = fmaxf(v, 0.f);
            if (Cf) Cf[(size_t)grow * N + gcol] = v;
            else if (out_f16) {
              _Float16 hv = (_Float16)v;
              Cb[(size_t)grow * N + gcol] = *(ushort*)&hv;
            } else {
              Cb[(size_t)grow * N + gcol] = f2bf(v);
            }
          }
        }
      }
    }
  }
}

// ------------------------------------------------------------ LayerNorm+ReLU
__global__ void ln_relu(const float* __restrict__ in, ushort* __restrict__ out,
                        const float* __restrict__ g, const float* __restrict__ be, int n)
{
  int gid = blockIdx.x * blockDim.x + threadIdx.x;
  int row = gid >> 6;
  int lane = threadIdx.x & 63;
  if (row >= n) return;
  float4 v = *reinterpret_cast<const float4*>(in + (size_t)row * HID + lane * 4);
  float s = v.x + v.y + v.z + v.w;
  float ss = v.x * v.x + v.y * v.y + v.z * v.z + v.w * v.w;
#pragma unroll
  for (int o = 1; o < 64; o <<= 1) { s += __shfl_xor(s, o); ss += __shfl_xor(ss, o); }
  float mu = s * (1.f / 256.f);
  float var = ss * (1.f / 256.f) - mu * mu;
  float inv = rsqrtf(var + 1e-5f);
  float4 gg = *reinterpret_cast<const float4*>(g + lane * 4);
  float4 bb = *reinterpret_cast<const float4*>(be + lane * 4);
  ushort4 o4;
  o4.x = f2bf(fmaxf((v.x - mu) * inv * gg.x + bb.x, 0.f));
  o4.y = f2bf(fmaxf((v.y - mu) * inv * gg.y + bb.y, 0.f));
  o4.z = f2bf(fmaxf((v.z - mu) * inv * gg.z + bb.z, 0.f));
  o4.w = f2bf(fmaxf((v.w - mu) * inv * gg.w + bb.w, 0.f));
  *reinterpret_cast<ushort4*>(out + (size_t)row * HID + lane * 4) = o4;
}

// ------------------------------------------------------------- CSR building
__global__ void csr_count2(const int* __restrict__ ei0, const int* __restrict__ ei1,
                           int* __restrict__ cnt0, int* __restrict__ cnt1)
{
  int e = blockIdx.x * blockDim.x + threadIdx.x;
  if (e >= 2 * EPRIME) return;
  int type = e >= EPRIME;
  int i = type ? e - EPRIME : e;
  const int* ei = type ? ei1 : ei0;
  int* cnt = type ? cnt1 : cnt0;
  int d = (i < E_EDGES) ? ei[E_EDGES + i] : (i - E_EDGES);
  atomicAdd(&cnt[d], 1);
}

// --- hierarchical exclusive scan over cnt0,cnt1 (padded to NPAD with zeros)
__global__ __launch_bounds__(256) void scan_p1(const int* __restrict__ cnt0,
                                               const int* __restrict__ cnt1,
                                               int* __restrict__ bsums)
{
  int type = blockIdx.x >= SCAN_NBLK;
  int blk = type ? blockIdx.x - SCAN_NBLK : blockIdx.x;
  const int* cnt = type ? cnt1 : cnt0;
  int4 v = reinterpret_cast<const int4*>(cnt)[blk * 256 + threadIdx.x];
  int s = v.x + v.y + v.z + v.w;
#pragma unroll
  for (int o = 1; o < 64; o <<= 1) s += __shfl_xor(s, o);
  __shared__ int wt[4];
  if ((threadIdx.x & 63) == 0) wt[threadIdx.x >> 6] = s;
  __syncthreads();
  if (threadIdx.x == 0) bsums[blockIdx.x] = wt[0] + wt[1] + wt[2] + wt[3];
}

__global__ void scan_p2(const int* __restrict__ bsums, int* __restrict__ boffs,
                        int* __restrict__ offs0, int* __restrict__ offs1)
{
  int t = threadIdx.x;
  if (t < 2) {
    int run = 0;
    for (int i = 0; i < SCAN_NBLK; i++) {
      boffs[t * SCAN_NBLK + i] = run;
      run += bsums[t * SCAN_NBLK + i];
    }
  }
  if (t == 2) offs0[N_NODES] = EPRIME;
  if (t == 3) offs1[N_NODES] = EPRIME;
}

__global__ __launch_bounds__(256) void scan_p3(
    const int* __restrict__ cnt0, const int* __restrict__ cnt1,
    const int* __restrict__ boffs,
    int* __restrict__ offs0, int* __restrict__ cur0,
    int* __restrict__ offs1, int* __restrict__ cur1)
{
  int type = blockIdx.x >= SCAN_NBLK;
  int blk = type ? blockIdx.x - SCAN_NBLK : blockIdx.x;
  const int* cnt = type ? cnt1 : cnt0;
  int* offs = type ? offs1 : offs0;
  int* cur  = type ? cur1 : cur0;
  const int tid = threadIdx.x, lane = tid & 63, wv = tid >> 6;
  int4 v = reinterpret_cast<const int4*>(cnt)[blk * 256 + tid];
  int e1 = v.x, e2 = e1 + v.y, e3 = e2 + v.z, T = e3 + v.w;
  int incl = T;
#pragma unroll
  for (int o = 1; o < 64; o <<= 1) {
    int nb = __shfl_up(incl, o);
    if (lane >= o) incl += nb;
  }
  __shared__ int wt[4];
  if (lane == 63) wt[wv] = incl;
  __syncthreads();
  int wexcl = 0;
  for (int i = 0; i < wv; i++) wexcl += wt[i];
  int base = boffs[blockIdx.x] + wexcl + (incl - T);
  int idx = blk * 1024 + tid * 4;
  int4 o4 = make_int4(base, base + e1, base + e2, base + e3);
  if (idx + 3 < N_NODES) {
    reinterpret_cast<int4*>(offs)[idx >> 2] = o4;
    reinterpret_cast<int4*>(cur)[idx >> 2] = o4;
  } else {
    if (idx + 0 < N_NODES) { offs[idx + 0] = o4.x; cur[idx + 0] = o4.x; }
    if (idx + 1 < N_NODES) { offs[idx + 1] = o4.y; cur[idx + 1] = o4.y; }
    if (idx + 2 < N_NODES) { offs[idx + 2] = o4.z; cur[idx + 2] = o4.z; }
    if (idx + 3 < N_NODES) { offs[idx + 3] = o4.w; cur[idx + 3] = o4.w; }
  }
}

__global__ void csr_scatter2(const int* __restrict__ ei0, const int* __restrict__ ei1,
                             int* __restrict__ cur0, int* __restrict__ cur1,
                             int* __restrict__ csr0, int* __restrict__ csr1)
{
  int e = blockIdx.x * blockDim.x + threadIdx.x;
  if (e >= 2 * EPRIME) return;
  int type = e >= EPRIME;
  int i = type ? e - EPRIME : e;
  const int* ei = type ? ei1 : ei0;
  int* cur = type ? cur1 : cur0;
  int* csr = type ? csr1 : csr0;
  int d = (i < E_EDGES) ? ei[E_EDGES + i] : (i - E_EDGES);
  int s = (i < E_EDGES) ? ei[i] : (i - E_EDGES);
  int pos = atomicAdd(&cur[d], 1);
  csr[pos] = s;
}

__global__ void csr_sort2(const int* __restrict__ offs0, int* __restrict__ csr0,
                          const int* __restrict__ offs1, int* __restrict__ csr1)
{
  int d = blockIdx.x * blockDim.x + threadIdx.x;
  if (d >= 2 * N_NODES) return;
  int type = d >= N_NODES;
  int i = type ? d - N_NODES : d;
  const int* offs = type ? offs1 : offs0;
  int* csr = type ? csr1 : csr0;
  int b = offs[i], e = offs[i + 1];
  for (int p = b + 1; p < e; p++) {
    int v = csr[p];
    int j = p - 1;
    while (j >= b && csr[j] > v) { csr[j + 1] = csr[j]; j--; }
    csr[j + 1] = v;
  }
}

// --------------------------------- all weight transposes/casts in one kernel
#define WSEG0 262144              // W0t   [256][1024]
#define WSEG1 (WSEG0 + 65536)     // W1t   [256][256]
#define WSEG2 (WSEG1 + 524288)    // WcatT [L][1024][256]
#define WSEG3 (WSEG2 + 262144)    // projcatT [L][256][512]
#define WSEG4 (WSEG3 + 65536)     // hW0t  [256][256]
#define WSEG5 (WSEG4 + 32768)     // hW1t  [128][256]
__global__ void wtrans_all(const float* __restrict__ pre_W0, const float* __restrict__ pre_W1,
                           const float* __restrict__ Wl, const float* __restrict__ Wr,
                           const float* __restrict__ proj_W,
                           const float* __restrict__ head_W0, const float* __restrict__ head_W1,
                           ushort* __restrict__ W0t, ushort* __restrict__ W1t,
                           ushort* __restrict__ WcatT, ushort* __restrict__ projcatT,
                           ushort* __restrict__ hW0t, ushort* __restrict__ hW1t)
{
  int i = blockIdx.x * blockDim.x + threadIdx.x;
  if (i < WSEG0) {
    int nrow = i >> 10, k = i & 1023;
    W0t[i] = f2bf(pre_W0[(size_t)k * 256 + nrow]);
  } else if (i < WSEG1) {
    int j = i - WSEG0;
    int nrow = j >> 8, k = j & 255;
    W1t[j] = f2bf(pre_W1[(size_t)k * 256 + nrow]);
  } else if (i < WSEG2) {
    int j = i - WSEG1;
    int l = j >> 18;
    int rem = j & 262143;
    int c = rem >> 8, k = rem & 255;
    int t = c >> 9, half = (c >> 8) & 1, cc = c & 255;
    const float* W = half ? Wr : Wl;
    WcatT[j] = f2bf(W[(((size_t)l * NTYPES + t) * 256 + k) * 256 + cc]);
  } else if (i < WSEG3) {
    int j = i - WSEG2;
    int l = j >> 17;
    int rem = j & 131071;
    int n = rem >> 9, k = rem & 511;
    int t = k >> 8, kk = k & 255;
    projcatT[j] = f2bf(proj_W[(((size_t)l * NTYPES + t) * 256 + kk) * 256 + n]);
  } else if (i < WSEG4) {
    int j = i - WSEG3;
    int nrow = j >> 8, k = j & 255;
    hW0t[j] = f2bf(head_W0[(size_t)k * 256 + nrow]);
  } else if (i < WSEG5) {
    int j = i - WSEG4;
    int nrow = j >> 8, k = j & 255;
    hW1t[j] = (nrow < OUT_DIM) ? f2bf(head_W1[(size_t)k * OUT_DIM + nrow]) : (ushort)0;
  }
}

// --------------------------------------------------------- DPP 8-lane reduce
__device__ __forceinline__ float dpp8_sum(float p) {
  // sum over lanes (l & ~7)..(l | 7): xor1, xor2 (quad_perm), then half-mirror
  p += __int_as_float(__builtin_amdgcn_update_dpp(0, __float_as_int(p), 0xB1, 0xF, 0xF, true));
  p += __int_as_float(__builtin_amdgcn_update_dpp(0, __float_as_int(p), 0x4E, 0xF, 0xF, true));
  p += __int_as_float(__builtin_amdgcn_update_dpp(0, __float_as_int(p), 0x141, 0xF, 0xF, true));
  return p;
}

__device__ __forceinline__ h8v leaky8(h8v x) {
  const _Float16 c = (_Float16)0.2f;
  h8v y = x * c;
#if __has_builtin(__builtin_elementwise_max)
  return __builtin_elementwise_max(x, y);
#else
  h8v r;
#pragma unroll
  for (int i = 0; i < 8; i++) r[i] = x[i] > y[i] ? x[i] : y[i];
  return r;
#endif
}

__device__ __forceinline__ float dot8(h8v e, const h2v* a) {
  h2v e0 = {e[0], e[1]}, e1 = {e[2], e[3]}, e2 = {e[4], e[5]}, e3 = {e[6], e[7]};
#if __has_builtin(__builtin_amdgcn_fdot2)
  float s = __builtin_amdgcn_fdot2(e0, a[0], 0.f, false);
  s = __builtin_amdgcn_fdot2(e1, a[1], s, false);
  s = __builtin_amdgcn_fdot2(e2, a[2], s, false);
  s = __builtin_amdgcn_fdot2(e3, a[3], s, false);
  return s;
#else
  float s = 0.f;
#pragma unroll
  for (int i = 0; i < 8; i++) s += (float)e[i] * (float)a[i >> 1][i & 1];
  return s;
#endif
}

// ---------------------------------------------- GATv2: dst-centric online SM
// one wave per dst; lanes 0-31 = even edges, 32-63 = odd; 4 edges in flight.
// lane li owns 8 channels (16 B fp16); head = li>>3; DPP reduce over 8 lanes.
__global__ __launch_bounds__(256) void gat_edge3(
    const _Float16* __restrict__ xlr,   // [MP,1024] fp16
    const int* __restrict__ offs0, const int* __restrict__ csr0,
    const int* __restrict__ offs1, const int* __restrict__ csr1,
    const float* __restrict__ att,      // [2*256] layer base
    const float* __restrict__ bias,     // [2*256] layer base
    ushort* __restrict__ out, int nblk_per_type)
{
  const int type = blockIdx.x >= nblk_per_type;
  const int bid = type ? blockIdx.x - nblk_per_type : blockIdx.x;
  const int wid = (bid * 256 + threadIdx.x) >> 6;
  if (wid >= N_NODES) return;
  const int lane = threadIdx.x & 63;
  const int half = lane >> 5, li = lane & 31;
  const int* offs = type ? offs1 : offs0;
  const int* csr  = type ? csr1 : csr0;
  const int xl_col = type ? 512 : 0;

  // att (8 ch/lane) -> packed fp16 pairs
  const float* ap = att + type * 256 + li * 8;
  h2v a[4];
#pragma unroll
  for (int i = 0; i < 4; i++) {
    a[i][0] = (_Float16)ap[2 * i];
    a[i][1] = (_Float16)ap[2 * i + 1];
  }
  const h8v xr = *reinterpret_cast<const h8v*>(xlr + (size_t)wid * 1024 + xl_col + 256 + li * 8);

  const int beg = offs[wid], end = offs[wid + 1];
  const float L2E = 1.44269504f;
  float m = -1e30f, den = 0.f;
  float acc[8];
#pragma unroll
  for (int i = 0; i < 8; i++) acc[i] = 0.f;

  const int ng = (end - beg + 3) >> 2;
  for (int g = 0; g < ng; g++) {
    const int j0 = beg + 4 * g + half;
    const int j1 = j0 + 2;
    const bool v0 = j0 < end, v1 = j1 < end;
    const int s0 = csr[v0 ? j0 : beg];
    const int s1 = csr[v1 ? j1 : beg];
    const h8v hs0 = *reinterpret_cast<const h8v*>(xlr + (size_t)s0 * 1024 + xl_col + li * 8);
    const h8v hs1 = *reinterpret_cast<const h8v*>(xlr + (size_t)s1 * 1024 + xl_col + li * 8);
    float p0 = dpp8_sum(dot8(leaky8(hs0 + xr), a));
    float p1 = dpp8_sum(dot8(leaky8(hs1 + xr), a));
    if (!v0) p0 = -INFINITY;
    if (!v1) p1 = -INFINITY;
    const float pm = fmaxf(p0, p1);
    if (__any(pm > m + 4.f)) {           // defer-max rescale (rare)
      const float nm = fmaxf(m, pm);
      const float so = exp2f((m - nm) * L2E);
      den *= so;
#pragma unroll
      for (int i = 0; i < 8; i++) acc[i] *= so;
      m = nm;
    }
    const float w0 = exp2f((p0 - m) * L2E);
    const float w1 = exp2f((p1 - m) * L2E);
    den += w0 + w1;
#pragma unroll
    for (int i = 0; i < 8; i++) {
      acc[i] = fmaf((float)hs0[i], w0, acc[i]);
      acc[i] = fmaf((float)hs1[i], w1, acc[i]);
    }
  }

  // merge the two halves
  const float mo  = __shfl_xor(m, 32);
  const float dno = __shfl_xor(den, 32);
  const float ms = fmaxf(m, mo);
  const float fa = exp2f((m - ms) * L2E);
  const float fb = exp2f((mo - ms) * L2E);
  const float r = 1.f / (den * fa + dno * fb + 1e-16f);
  float of[8];
#pragma unroll
  for (int i = 0; i < 8; i++)
    of[i] = (acc[i] * fa + __shfl_xor(acc[i], 32) * fb) * r;

  if (half == 0) {
    const float* bp = bias + type * 256 + li * 8;
    uint4 o;
    uint pk[4];
#pragma unroll
    for (int i = 0; i < 4; i++) {
      const uint lo = f2bf(of[2 * i] + bp[2 * i]);
      const uint hi = f2bf(of[2 * i + 1] + bp[2 * i + 1]);
      pk[i] = lo | (hi << 16);
    }
    o.x = pk[0]; o.y = pk[1]; o.z = pk[2]; o.w = pk[3];
    *reinterpret_cast<uint4*>(out + (size_t)wid * 512 + type * 256 + li * 8) = o;
  }
}

// ----------------------------------------------------------------- launcher
extern "C" void kernel_launch(void* const* d_in, const int* in_sizes, int n_in,
                              void* d_out, int out_size, void* d_ws, size_t ws_size,
                              hipStream_t stream)
{
  const float* x        = (const float*)d_in[0];
  const int*   ei0      = (const int*)d_in[1];
  const int*   ei1      = (const int*)d_in[2];
  const float* pre_W0   = (const float*)d_in[3];
  const float* pre_b0   = (const float*)d_in[4];
  const float* pre_g0   = (const float*)d_in[5];
  const float* pre_be0  = (const float*)d_in[6];
  const float* pre_W1   = (const float*)d_in[7];
  const float* pre_b1   = (const float*)d_in[8];
  const float* pre_g1   = (const float*)d_in[9];
  const float* pre_be1  = (const float*)d_in[10];
  const float* gat_Wl   = (const float*)d_in[11];
  const float* gat_Wr   = (const float*)d_in[12];
  const float* gat_att  = (const float*)d_in[13];
  const float* gat_bias = (const float*)d_in[14];
  const float* proj_W   = (const float*)d_in[15];
  const float* proj_b   = (const float*)d_in[16];
  const float* head_W0  = (const float*)d_in[17];
  const float* head_b0  = (const float*)d_in[18];
  const float* head_W1  = (const float*)d_in[19];
  const float* head_b1  = (const float*)d_in[20];
  float* outp = (float*)d_out;

  // ---- workspace arena (all segments 16B-aligned)
  char* ws = (char*)d_ws;
  ushort* xlr_b = (ushort*)ws; ws += (size_t)MP * 1024 * 2;   // fp16 GAT input
  ushort* hb    = (ushort*)ws; ws += (size_t)MP * 256 * 2;
  ushort* outt  = (ushort*)ws; ws += (size_t)MP * 512 * 2;   // gat concat out
  float*  tmp   = (float*)outt;                               // alias: pre-LN f32 buf
  ushort* hbuf  = (ushort*)outt;                              // alias: head0 out
  ushort* W0t      = (ushort*)ws; ws += (size_t)256 * 1024 * 2;
  ushort* W1t      = (ushort*)ws; ws += (size_t)256 * 256 * 2;
  ushort* WcatT    = (ushort*)ws; ws += (size_t)LAYERS * 1024 * 256 * 2;
  ushort* projcatT = (ushort*)ws; ws += (size_t)LAYERS * 256 * 512 * 2;
  ushort* hW0t     = (ushort*)ws; ws += (size_t)256 * 256 * 2;
  ushort* hW1t     = (ushort*)ws; ws += (size_t)128 * 256 * 2;
  int* cnt0  = (int*)ws; ws += (size_t)NPAD * 4;
  int* cnt1  = (int*)ws; ws += (size_t)NPAD * 4;
  int* offs0 = (int*)ws; ws += (size_t)(N_NODES + 4) * 4;
  int* offs1 = (int*)ws; ws += (size_t)(N_NODES + 4) * 4;
  int* cur0  = (int*)ws; ws += (size_t)N_NODES * 4;
  int* cur1  = (int*)ws; ws += (size_t)N_NODES * 4;
  int* bsums = (int*)ws; ws += (size_t)128 * 4;
  int* boffs = (int*)ws; ws += (size_t)128 * 4;
  int* csr0  = (int*)ws; ws += (size_t)EPRIME * 4;
  int* csr1  = (int*)ws; ws += (size_t)EPRIME * 4;

  // ---- CSR build (deterministic via per-bucket sort)
  hipMemsetAsync(cnt0, 0, (size_t)2 * NPAD * 4, stream);   // cnt0+cnt1 contiguous
  const int gE2 = (2 * EPRIME + 255) / 256;
  csr_count2<<<gE2, 256, 0, stream>>>(ei0, ei1, cnt0, cnt1);
  scan_p1<<<2 * SCAN_NBLK, 256, 0, stream>>>(cnt0, cnt1, bsums);
  scan_p2<<<1, 64, 0, stream>>>(bsums, boffs, offs0, offs1);
  scan_p3<<<2 * SCAN_NBLK, 256, 0, stream>>>(cnt0, cnt1, boffs, offs0, cur0, offs1, cur1);
  csr_scatter2<<<gE2, 256, 0, stream>>>(ei0, ei1, cur0, cur1, csr0, csr1);
  csr_sort2<<<(2 * N_NODES + 255) / 256, 256, 0, stream>>>(offs0, csr0, offs1, csr1);

  // ---- weights -> bf16 K-major (single launch)
  wtrans_all<<<WSEG5 / 256, 256, 0, stream>>>(pre_W0, pre_W1, gat_Wl, gat_Wr, proj_W,
                                              head_W0, head_W1,
                                              W0t, W1t, WcatT, projcatT, hW0t, hW1t);

  const dim3 blk(256);
  const int gy = MP / 128;   // 391
  const int gln = (N_NODES * 64 + 255) / 256;   // 12500

  // ---- preprocessor MLP (pre0 reads f32 x directly, casts in staging)
  gemm_k<true><<<dim3(4, gy), blk, 0, stream>>>(x, W0t, 1024, N_NODES, 256,
                                                tmp, nullptr, pre_b0, nullptr, 0, 0);
  ln_relu<<<gln, 256, 0, stream>>>(tmp, hb, pre_g0, pre_be0, N_NODES);
  gemm_k<false><<<dim3(4, gy), blk, 0, stream>>>(hb, W1t, 256, N_NODES, 256,
                                                 tmp, nullptr, pre_b1, nullptr, 0, 0);
  ln_relu<<<gln, 256, 0, stream>>>(tmp, hb, pre_g1, pre_be1, N_NODES);

  // ---- GNN layers
  for (int l = 0; l < LAYERS; l++) {
    gemm_k<false><<<dim3(16, gy), blk, 0, stream>>>(hb, WcatT + (size_t)l * 1024 * 256,
                                                    256, N_NODES, 1024,
                                                    nullptr, xlr_b, nullptr, nullptr, 0, 1);
    gat_edge3<<<2 * gln, 256, 0, stream>>>(
        (const _Float16*)xlr_b, offs0, csr0, offs1, csr1,
        gat_att  + (size_t)l * NTYPES * NHEAD * DHEAD,
        gat_bias + (size_t)l * NTYPES * HID,
        outt, gln);
    gemm_k<false><<<dim3(4, gy), blk, 0, stream>>>(
        outt, projcatT + (size_t)l * 256 * 512, 512, N_NODES, 256,
        nullptr, hb,
        proj_b + (size_t)(l * NTYPES + 0) * HID,
        proj_b + (size_t)(l * NTYPES + 1) * HID, 1, 0);
  }

  // ---- prediction head
  gemm_k<false><<<dim3(4, gy), blk, 0, stream>>>(hb, hW0t, 256, N_NODES, 256,
                                                 nullptr, hbuf, head_b0, nullptr, 1, 0);
  gemm_k<false><<<dim3(1, gy), blk, 0, stream>>>(hbuf, hW1t, 256, N_NODES, OUT_DIM,
                                                 outp, nullptr, head_b1, nullptr, 0, 0);
}

// Round 6
// 778.602 us; speedup vs baseline: 3.3062x; 1.1159x over previous
//
#include <hip/hip_runtime.h>
#include <hip/hip_bf16.h>
#include <math.h>

#define N_NODES 50000
#define MP      50048          // 391 * 128, padded row count
#define E_EDGES 500000
#define EPRIME  (E_EDGES + N_NODES)
#define HID     256
#define PRE_IN  1024
#define OUT_DIM 64
#define NHEAD   4
#define DHEAD   64
#define LAYERS  2
#define NTYPES  2

#define SCAN_NBLK 49                     // ceil(50000/1024)
#define NPAD      (SCAN_NBLK * 1024)     // 50176

typedef __attribute__((ext_vector_type(8))) short short8v;
typedef __attribute__((ext_vector_type(4))) float f32x4;
typedef _Float16 h2v __attribute__((ext_vector_type(2)));
typedef _Float16 h8v __attribute__((ext_vector_type(8)));

__device__ __forceinline__ ushort f2bf(float f) {
  uint u = __float_as_uint(f);
  u += 0x7FFF + ((u >> 16) & 1);          // RNE
  return (ushort)(u >> 16);
}
__device__ __forceinline__ float bf2f(ushort u) {
  return __uint_as_float(((uint)u) << 16);
}

// ------------------------------------------------------------- bf16 MFMA GEMM
// C[M,N] = op(A[M,K] @ Bt[N,K]^T + bias(+bias2)); Bt bf16 K-major, rows padded.
// A: bf16 K-major (AF32=false) or f32 K-major (AF32=true, rows >= M read as 0).
// BM=128, BN=64, BK=32; 4 waves, wave-tile 64x32 (acc[4][2], 8 MFMA/K-step).
// T1: bijective XCD-chunked blockIdx swizzle (m204) -- same-stripe column
//     tiles land on ONE XCD so its L2 fetches each A-stripe once (round 5
//     showed 2x FETCH overfetch of x from the 4 col-tiles spreading across
//     4 XCD L2s).
// T14 (AF32 path): next K-step's A f32 loads are issued into registers before
//     this K-step's barrier+MFMA; ds_write happens next iteration -> HBM
//     latency hides under compute instead of serializing inside staging.
// LDS layout byte = row*64 + (kc ^ ((row>>1)&3))*16 (XOR swizzle on both sides).
template<bool AF32>
__global__ __launch_bounds__(256) void gemm_k(
    const void* __restrict__ Ap,
    const ushort* __restrict__ Bt,
    int K, int M, int N,
    float*  __restrict__ Cf,          // f32 out (or null)
    ushort* __restrict__ Cb,          // 16-bit out (or null)
    const float* __restrict__ bias,   // [N] or null
    const float* __restrict__ bias2,  // [N] or null (added too)
    int do_relu, int out_f16)         // out_f16: Cb holds fp16 instead of bf16
{
  __shared__ ushort As[128 * 32];     // 8 KB
  __shared__ ushort Bs[64 * 32];      // 4 KB
  const int tid = threadIdx.x;
  const int l   = tid & 63;
  const int w   = tid >> 6;
  const int wm  = w & 1;              // row half (64 rows)
  const int wn  = w >> 1;             // col quarter (32 cols)

  // ---- T1: bijective XCD-chunked swizzle (m204)
  const int nwg  = gridDim.x * gridDim.y;
  const int orig = blockIdx.y * gridDim.x + blockIdx.x;
  const int qq   = nwg >> 3, rr = nwg & 7;
  const int xcd  = orig & 7;
  const int wgid = ((xcd < rr) ? xcd * (qq + 1) : rr * (qq + 1) + (xcd - rr) * qq)
                   + (orig >> 3);
  const int bm = (wgid / gridDim.x) * 128;
  const int bn = (wgid % gridDim.x) * 64;

  f32x4 acc[4][2];
#pragma unroll
  for (int m = 0; m < 4; m++)
#pragma unroll
    for (int n = 0; n < 2; n++) acc[m][n] = (f32x4){0.f, 0.f, 0.f, 0.f};

  const int srow  = l >> 2;   // 0..15
  const int sslot = l & 3;    // kc slot

  // B staging geometry: one 16B slot per thread, dest = tid*16 (wave-linear)
  const int brow  = tid >> 2;        // 0..63
  const int bslot = tid & 3;
  const int bkc   = bslot ^ ((brow >> 1) & 3);

  // ---- T14 prologue: prefetch K-step 0 of A into registers (AF32 only)
  float4 pf[2][2];
  if constexpr (AF32) {
#pragma unroll
    for (int i = 0; i < 2; i++) {
      const int row = w * 32 + i * 16 + srow;
      const int kc  = sslot ^ ((row >> 1) & 3);
      pf[i][0] = make_float4(0.f, 0.f, 0.f, 0.f);
      pf[i][1] = make_float4(0.f, 0.f, 0.f, 0.f);
      if (bm + row < M) {
        const float* ga = (const float*)Ap + (size_t)(bm + row) * K + kc * 8;
        pf[i][0] = *reinterpret_cast<const float4*>(ga);
        pf[i][1] = *reinterpret_cast<const float4*>(ga + 4);
      }
    }
  }

  for (int k0 = 0; k0 < K; k0 += 32) {
    // ---- stage B tile 64x32
    {
      const ushort* gb = Bt + (size_t)(bn + brow) * K + k0 + bkc * 8;
      __builtin_amdgcn_global_load_lds(
          (const __attribute__((address_space(1))) uint*)gb,
          (__attribute__((address_space(3))) uint*)((char*)Bs + tid * 16), 16, 0, 0);
    }
    // ---- stage A tile 128x32: wave w covers rows [w*32, w*32+32)
    if constexpr (AF32) {
      // write the prefetched registers (loaded ~1 full iteration ago)
#pragma unroll
      for (int i = 0; i < 2; i++) {
        const int row = w * 32 + i * 16 + srow;
        const uint off = (uint)row * 64 + (uint)sslot * 16;
        short8v s;
        s[0] = (short)f2bf(pf[i][0].x); s[1] = (short)f2bf(pf[i][0].y);
        s[2] = (short)f2bf(pf[i][0].z); s[3] = (short)f2bf(pf[i][0].w);
        s[4] = (short)f2bf(pf[i][1].x); s[5] = (short)f2bf(pf[i][1].y);
        s[6] = (short)f2bf(pf[i][1].z); s[7] = (short)f2bf(pf[i][1].w);
        *reinterpret_cast<short8v*>((char*)As + off) = s;
      }
      // issue next K-step's loads now; consumed next iteration (T14)
      if (k0 + 32 < K) {
#pragma unroll
        for (int i = 0; i < 2; i++) {
          const int row = w * 32 + i * 16 + srow;
          const int kc  = sslot ^ ((row >> 1) & 3);
          if (bm + row < M) {
            const float* ga = (const float*)Ap + (size_t)(bm + row) * K + (k0 + 32) + kc * 8;
            pf[i][0] = *reinterpret_cast<const float4*>(ga);
            pf[i][1] = *reinterpret_cast<const float4*>(ga + 4);
          }
          // rows >= M: pf stays zero from the prologue
        }
      }
    } else {
#pragma unroll
      for (int i = 0; i < 2; i++) {
        const int row = w * 32 + i * 16 + srow;
        const int kc  = sslot ^ ((row >> 1) & 3);
        const uint off = (uint)row * 64 + (uint)sslot * 16;
        const ushort* ga = (const ushort*)Ap + (size_t)(bm + row) * K + k0 + kc * 8;
        __builtin_amdgcn_global_load_lds(
            (const __attribute__((address_space(1))) uint*)ga,
            (__attribute__((address_space(3))) uint*)((char*)As + off), 16, 0, 0);
      }
    }
    __syncthreads();

    short8v a[4], b[2];
#pragma unroll
    for (int m = 0; m < 4; m++) {
      const int row = wm * 64 + m * 16 + (l & 15);
      const int kc  = (l >> 4) ^ ((row >> 1) & 3);
      a[m] = *(const short8v*)((const char*)As + row * 64 + kc * 16);
    }
#pragma unroll
    for (int n = 0; n < 2; n++) {
      const int row = wn * 32 + n * 16 + (l & 15);
      const int kc  = (l >> 4) ^ ((row >> 1) & 3);
      b[n] = *(const short8v*)((const char*)Bs + row * 64 + kc * 16);
    }
#pragma unroll
    for (int m = 0; m < 4; m++)
#pragma unroll
      for (int n = 0; n < 2; n++)
        acc[m][n] = __builtin_amdgcn_mfma_f32_16x16x32_bf16(a[m], b[n], acc[m][n], 0, 0, 0);
    __syncthreads();
  }

  // epilogue: C/D map col=lane&15, row=(lane>>4)*4+reg
  const int crow0 = bm + wm * 64 + (l >> 4) * 4;
  const int ccol0 = bn + wn * 32 + (l & 15);
#pragma unroll
  for (int m = 0; m < 4; m++) {
#pragma unroll
    for (int j = 0; j < 4; j++) {
      const int grow = crow0 + m * 16 + j;
      if (grow < M) {
#pragma unroll
        for (int n = 0; n < 2; n++) {
          const int gcol = ccol0 + n * 16;
          if (gcol < N) {
            float v = acc[m][n][j];
            if (bias)  v += bias[gcol];
            if (bias2) v += bias2[gcol];
            if (do_relu) v = fmaxf(v, 0.f);
            if (Cf) Cf[(size_t)grow * N + gcol] = v;
            else if (out_f16) {
              _Float16 hv = (_Float16)v;
              Cb[(size_t)grow * N + gcol] = *(ushort*)&hv;
            } else {
              Cb[(size_t)grow * N + gcol] = f2bf(v);
            }
          }
        }
      }
    }
  }
}

// ------------------------------------------------------------ LayerNorm+ReLU
__global__ void ln_relu(const float* __restrict__ in, ushort* __restrict__ out,
                        const float* __restrict__ g, const float* __restrict__ be, int n)
{
  int gid = blockIdx.x * blockDim.x + threadIdx.x;
  int row = gid >> 6;
  int lane = threadIdx.x & 63;
  if (row >= n) return;
  float4 v = *reinterpret_cast<const float4*>(in + (size_t)row * HID + lane * 4);
  float s = v.x + v.y + v.z + v.w;
  float ss = v.x * v.x + v.y * v.y + v.z * v.z + v.w * v.w;
#pragma unroll
  for (int o = 1; o < 64; o <<= 1) { s += __shfl_xor(s, o); ss += __shfl_xor(ss, o); }
  float mu = s * (1.f / 256.f);
  float var = ss * (1.f / 256.f) - mu * mu;
  float inv = rsqrtf(var + 1e-5f);
  float4 gg = *reinterpret_cast<const float4*>(g + lane * 4);
  float4 bb = *reinterpret_cast<const float4*>(be + lane * 4);
  ushort4 o4;
  o4.x = f2bf(fmaxf((v.x - mu) * inv * gg.x + bb.x, 0.f));
  o4.y = f2bf(fmaxf((v.y - mu) * inv * gg.y + bb.y, 0.f));
  o4.z = f2bf(fmaxf((v.z - mu) * inv * gg.z + bb.z, 0.f));
  o4.w = f2bf(fmaxf((v.w - mu) * inv * gg.w + bb.w, 0.f));
  *reinterpret_cast<ushort4*>(out + (size_t)row * HID + lane * 4) = o4;
}

// ------------------------------------------------------------- CSR building
__global__ void csr_count2(const int* __restrict__ ei0, const int* __restrict__ ei1,
                           int* __restrict__ cnt0, int* __restrict__ cnt1)
{
  int e = blockIdx.x * blockDim.x + threadIdx.x;
  if (e >= 2 * EPRIME) return;
  int type = e >= EPRIME;
  int i = type ? e - EPRIME : e;
  const int* ei = type ? ei1 : ei0;
  int* cnt = type ? cnt1 : cnt0;
  int d = (i < E_EDGES) ? ei[E_EDGES + i] : (i - E_EDGES);
  atomicAdd(&cnt[d], 1);
}

// --- hierarchical exclusive scan over cnt0,cnt1 (padded to NPAD with zeros)
__global__ __launch_bounds__(256) void scan_p1(const int* __restrict__ cnt0,
                                               const int* __restrict__ cnt1,
                                               int* __restrict__ bsums)
{
  int type = blockIdx.x >= SCAN_NBLK;
  int blk = type ? blockIdx.x - SCAN_NBLK : blockIdx.x;
  const int* cnt = type ? cnt1 : cnt0;
  int4 v = reinterpret_cast<const int4*>(cnt)[blk * 256 + threadIdx.x];
  int s = v.x + v.y + v.z + v.w;
#pragma unroll
  for (int o = 1; o < 64; o <<= 1) s += __shfl_xor(s, o);
  __shared__ int wt[4];
  if ((threadIdx.x & 63) == 0) wt[threadIdx.x >> 6] = s;
  __syncthreads();
  if (threadIdx.x == 0) bsums[blockIdx.x] = wt[0] + wt[1] + wt[2] + wt[3];
}

__global__ void scan_p2(const int* __restrict__ bsums, int* __restrict__ boffs,
                        int* __restrict__ offs0, int* __restrict__ offs1)
{
  int t = threadIdx.x;
  if (t < 2) {
    int run = 0;
    for (int i = 0; i < SCAN_NBLK; i++) {
      boffs[t * SCAN_NBLK + i] = run;
      run += bsums[t * SCAN_NBLK + i];
    }
  }
  if (t == 2) offs0[N_NODES] = EPRIME;
  if (t == 3) offs1[N_NODES] = EPRIME;
}

__global__ __launch_bounds__(256) void scan_p3(
    const int* __restrict__ cnt0, const int* __restrict__ cnt1,
    const int* __restrict__ boffs,
    int* __restrict__ offs0, int* __restrict__ cur0,
    int* __restrict__ offs1, int* __restrict__ cur1)
{
  int type = blockIdx.x >= SCAN_NBLK;
  int blk = type ? blockIdx.x - SCAN_NBLK : blockIdx.x;
  const int* cnt = type ? cnt1 : cnt0;
  int* offs = type ? offs1 : offs0;
  int* cur  = type ? cur1 : cur0;
  const int tid = threadIdx.x, lane = tid & 63, wv = tid >> 6;
  int4 v = reinterpret_cast<const int4*>(cnt)[blk * 256 + tid];
  int e1 = v.x, e2 = e1 + v.y, e3 = e2 + v.z, T = e3 + v.w;
  int incl = T;
#pragma unroll
  for (int o = 1; o < 64; o <<= 1) {
    int nb = __shfl_up(incl, o);
    if (lane >= o) incl += nb;
  }
  __shared__ int wt[4];
  if (lane == 63) wt[wv] = incl;
  __syncthreads();
  int wexcl = 0;
  for (int i = 0; i < wv; i++) wexcl += wt[i];
  int base = boffs[blockIdx.x] + wexcl + (incl - T);
  int idx = blk * 1024 + tid * 4;
  int4 o4 = make_int4(base, base + e1, base + e2, base + e3);
  if (idx + 3 < N_NODES) {
    reinterpret_cast<int4*>(offs)[idx >> 2] = o4;
    reinterpret_cast<int4*>(cur)[idx >> 2] = o4;
  } else {
    if (idx + 0 < N_NODES) { offs[idx + 0] = o4.x; cur[idx + 0] = o4.x; }
    if (idx + 1 < N_NODES) { offs[idx + 1] = o4.y; cur[idx + 1] = o4.y; }
    if (idx + 2 < N_NODES) { offs[idx + 2] = o4.z; cur[idx + 2] = o4.z; }
    if (idx + 3 < N_NODES) { offs[idx + 3] = o4.w; cur[idx + 3] = o4.w; }
  }
}

__global__ void csr_scatter2(const int* __restrict__ ei0, const int* __restrict__ ei1,
                             int* __restrict__ cur0, int* __restrict__ cur1,
                             int* __restrict__ csr0, int* __restrict__ csr1)
{
  int e = blockIdx.x * blockDim.x + threadIdx.x;
  if (e >= 2 * EPRIME) return;
  int type = e >= EPRIME;
  int i = type ? e - EPRIME : e;
  const int* ei = type ? ei1 : ei0;
  int* cur = type ? cur1 : cur0;
  int* csr = type ? csr1 : csr0;
  int d = (i < E_EDGES) ? ei[E_EDGES + i] : (i - E_EDGES);
  int s = (i < E_EDGES) ? ei[i] : (i - E_EDGES);
  int pos = atomicAdd(&cur[d], 1);
  csr[pos] = s;
}

__global__ void csr_sort2(const int* __restrict__ offs0, int* __restrict__ csr0,
                          const int* __restrict__ offs1, int* __restrict__ csr1)
{
  int d = blockIdx.x * blockDim.x + threadIdx.x;
  if (d >= 2 * N_NODES) return;
  int type = d >= N_NODES;
  int i = type ? d - N_NODES : d;
  const int* offs = type ? offs1 : offs0;
  int* csr = type ? csr1 : csr0;
  int b = offs[i], e = offs[i + 1];
  for (int p = b + 1; p < e; p++) {
    int v = csr[p];
    int j = p - 1;
    while (j >= b && csr[j] > v) { csr[j + 1] = csr[j]; j--; }
    csr[j + 1] = v;
  }
}

// --------------------------------- all weight transposes/casts in one kernel
#define WSEG0 262144              // W0t   [256][1024]
#define WSEG1 (WSEG0 + 65536)     // W1t   [256][256]
#define WSEG2 (WSEG1 + 524288)    // WcatT [L][1024][256]
#define WSEG3 (WSEG2 + 262144)    // projcatT [L][256][512]
#define WSEG4 (WSEG3 + 65536)     // hW0t  [256][256]
#define WSEG5 (WSEG4 + 32768)     // hW1t  [128][256]
__global__ void wtrans_all(const float* __restrict__ pre_W0, const float* __restrict__ pre_W1,
                           const float* __restrict__ Wl, const float* __restrict__ Wr,
                           const float* __restrict__ proj_W,
                           const float* __restrict__ head_W0, const float* __restrict__ head_W1,
                           ushort* __restrict__ W0t, ushort* __restrict__ W1t,
                           ushort* __restrict__ WcatT, ushort* __restrict__ projcatT,
                           ushort* __restrict__ hW0t, ushort* __restrict__ hW1t)
{
  int i = blockIdx.x * blockDim.x + threadIdx.x;
  if (i < WSEG0) {
    int nrow = i >> 10, k = i & 1023;
    W0t[i] = f2bf(pre_W0[(size_t)k * 256 + nrow]);
  } else if (i < WSEG1) {
    int j = i - WSEG0;
    int nrow = j >> 8, k = j & 255;
    W1t[j] = f2bf(pre_W1[(size_t)k * 256 + nrow]);
  } else if (i < WSEG2) {
    int j = i - WSEG1;
    int l = j >> 18;
    int rem = j & 262143;
    int c = rem >> 8, k = rem & 255;
    int t = c >> 9, half = (c >> 8) & 1, cc = c & 255;
    const float* W = half ? Wr : Wl;
    WcatT[j] = f2bf(W[(((size_t)l * NTYPES + t) * 256 + k) * 256 + cc]);
  } else if (i < WSEG3) {
    int j = i - WSEG2;
    int l = j >> 17;
    int rem = j & 131071;
    int n = rem >> 9, k = rem & 511;
    int t = k >> 8, kk = k & 255;
    projcatT[j] = f2bf(proj_W[(((size_t)l * NTYPES + t) * 256 + kk) * 256 + n]);
  } else if (i < WSEG4) {
    int j = i - WSEG3;
    int nrow = j >> 8, k = j & 255;
    hW0t[j] = f2bf(head_W0[(size_t)k * 256 + nrow]);
  } else if (i < WSEG5) {
    int j = i - WSEG4;
    int nrow = j >> 8, k = j & 255;
    hW1t[j] = (nrow < OUT_DIM) ? f2bf(head_W1[(size_t)k * OUT_DIM + nrow]) : (ushort)0;
  }
}

// --------------------------------------------------------- DPP 8-lane reduce
__device__ __forceinline__ float dpp8_sum(float p) {
  // sum over lanes (l & ~7)..(l | 7): xor1, xor2 (quad_perm), then half-mirror
  p += __int_as_float(__builtin_amdgcn_update_dpp(0, __float_as_int(p), 0xB1, 0xF, 0xF, true));
  p += __int_as_float(__builtin_amdgcn_update_dpp(0, __float_as_int(p), 0x4E, 0xF, 0xF, true));
  p += __int_as_float(__builtin_amdgcn_update_dpp(0, __float_as_int(p), 0x141, 0xF, 0xF, true));
  return p;
}

__device__ __forceinline__ h8v leaky8(h8v x) {
  const _Float16 c = (_Float16)0.2f;
  h8v y = x * c;
#if __has_builtin(__builtin_elementwise_max)
  return __builtin_elementwise_max(x, y);
#else
  h8v r;
#pragma unroll
  for (int i = 0; i < 8; i++) r[i] = x[i] > y[i] ? x[i] : y[i];
  return r;
#endif
}

__device__ __forceinline__ float dot8(h8v e, const h2v* a) {
  h2v e0 = {e[0], e[1]}, e1 = {e[2], e[3]}, e2 = {e[4], e[5]}, e3 = {e[6], e[7]};
#if __has_builtin(__builtin_amdgcn_fdot2)
  float s = __builtin_amdgcn_fdot2(e0, a[0], 0.f, false);
  s = __builtin_amdgcn_fdot2(e1, a[1], s, false);
  s = __builtin_amdgcn_fdot2(e2, a[2], s, false);
  s = __builtin_amdgcn_fdot2(e3, a[3], s, false);
  return s;
#else
  float s = 0.f;
#pragma unroll
  for (int i = 0; i < 8; i++) s += (float)e[i] * (float)a[i >> 1][i & 1];
  return s;
#endif
}

// ---------------------------------------------- GATv2: dst-centric online SM
// one wave per dst; lanes 0-31 = even edges, 32-63 = odd; 4 edges in flight.
// lane li owns 8 channels (16 B fp16); head = li>>3; DPP reduce over 8 lanes.
__global__ __launch_bounds__(256) void gat_edge3(
    const _Float16* __restrict__ xlr,   // [MP,1024] fp16
    const int* __restrict__ offs0, const int* __restrict__ csr0,
    const int* __restrict__ offs1, const int* __restrict__ csr1,
    const float* __restrict__ att,      // [2*256] layer base
    const float* __restrict__ bias,     // [2*256] layer base
    ushort* __restrict__ out, int nblk_per_type)
{
  const int type = blockIdx.x >= nblk_per_type;
  const int bid = type ? blockIdx.x - nblk_per_type : blockIdx.x;
  const int wid = (bid * 256 + threadIdx.x) >> 6;
  if (wid >= N_NODES) return;
  const int lane = threadIdx.x & 63;
  const int half = lane >> 5, li = lane & 31;
  const int* offs = type ? offs1 : offs0;
  const int* csr  = type ? csr1 : csr0;
  const int xl_col = type ? 512 : 0;

  // att (8 ch/lane) -> packed fp16 pairs
  const float* ap = att + type * 256 + li * 8;
  h2v a[4];
#pragma unroll
  for (int i = 0; i < 4; i++) {
    a[i][0] = (_Float16)ap[2 * i];
    a[i][1] = (_Float16)ap[2 * i + 1];
  }
  const h8v xr = *reinterpret_cast<const h8v*>(xlr + (size_t)wid * 1024 + xl_col + 256 + li * 8);

  const int beg = offs[wid], end = offs[wid + 1];
  const float L2E = 1.44269504f;
  float m = -1e30f, den = 0.f;
  float acc[8];
#pragma unroll
  for (int i = 0; i < 8; i++) acc[i] = 0.f;

  const int ng = (end - beg + 3) >> 2;
  for (int g = 0; g < ng; g++) {
    const int j0 = beg + 4 * g + half;
    const int j1 = j0 + 2;
    const bool v0 = j0 < end, v1 = j1 < end;
    const int s0 = csr[v0 ? j0 : beg];
    const int s1 = csr[v1 ? j1 : beg];
    const h8v hs0 = *reinterpret_cast<const h8v*>(xlr + (size_t)s0 * 1024 + xl_col + li * 8);
    const h8v hs1 = *reinterpret_cast<const h8v*>(xlr + (size_t)s1 * 1024 + xl_col + li * 8);
    float p0 = dpp8_sum(dot8(leaky8(hs0 + xr), a));
    float p1 = dpp8_sum(dot8(leaky8(hs1 + xr), a));
    if (!v0) p0 = -INFINITY;
    if (!v1) p1 = -INFINITY;
    const float pm = fmaxf(p0, p1);
    if (__any(pm > m + 4.f)) {           // defer-max rescale (rare)
      const float nm = fmaxf(m, pm);
      const float so = exp2f((m - nm) * L2E);
      den *= so;
#pragma unroll
      for (int i = 0; i < 8; i++) acc[i] *= so;
      m = nm;
    }
    const float w0 = exp2f((p0 - m) * L2E);
    const float w1 = exp2f((p1 - m) * L2E);
    den += w0 + w1;
#pragma unroll
    for (int i = 0; i < 8; i++) {
      acc[i] = fmaf((float)hs0[i], w0, acc[i]);
      acc[i] = fmaf((float)hs1[i], w1, acc[i]);
    }
  }

  // merge the two halves
  const float mo  = __shfl_xor(m, 32);
  const float dno = __shfl_xor(den, 32);
  const float ms = fmaxf(m, mo);
  const float fa = exp2f((m - ms) * L2E);
  const float fb = exp2f((mo - ms) * L2E);
  const float r = 1.f / (den * fa + dno * fb + 1e-16f);
  float of[8];
#pragma unroll
  for (int i = 0; i < 8; i++)
    of[i] = (acc[i] * fa + __shfl_xor(acc[i], 32) * fb) * r;

  if (half == 0) {
    const float* bp = bias + type * 256 + li * 8;
    uint4 o;
    uint pk[4];
#pragma unroll
    for (int i = 0; i < 4; i++) {
      const uint lo = f2bf(of[2 * i] + bp[2 * i]);
      const uint hi = f2bf(of[2 * i + 1] + bp[2 * i + 1]);
      pk[i] = lo | (hi << 16);
    }
    o.x = pk[0]; o.y = pk[1]; o.z = pk[2]; o.w = pk[3];
    *reinterpret_cast<uint4*>(out + (size_t)wid * 512 + type * 256 + li * 8) = o;
  }
}

// ----------------------------------------------------------------- launcher
extern "C" void kernel_launch(void* const* d_in, const int* in_sizes, int n_in,
                              void* d_out, int out_size, void* d_ws, size_t ws_size,
                              hipStream_t stream)
{
  const float* x        = (const float*)d_in[0];
  const int*   ei0      = (const int*)d_in[1];
  const int*   ei1      = (const int*)d_in[2];
  const float* pre_W0   = (const float*)d_in[3];
  const float* pre_b0   = (const float*)d_in[4];
  const float* pre_g0   = (const float*)d_in[5];
  const float* pre_be0  = (const float*)d_in[6];
  const float* pre_W1   = (const float*)d_in[7];
  const float* pre_b1   = (const float*)d_in[8];
  const float* pre_g1   = (const float*)d_in[9];
  const float* pre_be1  = (const float*)d_in[10];
  const float* gat_Wl   = (const float*)d_in[11];
  const float* gat_Wr   = (const float*)d_in[12];
  const float* gat_att  = (const float*)d_in[13];
  const float* gat_bias = (const float*)d_in[14];
  const float* proj_W   = (const float*)d_in[15];
  const float* proj_b   = (const float*)d_in[16];
  const float* head_W0  = (const float*)d_in[17];
  const float* head_b0  = (const float*)d_in[18];
  const float* head_W1  = (const float*)d_in[19];
  const float* head_b1  = (const float*)d_in[20];
  float* outp = (float*)d_out;

  // ---- workspace arena (all segments 16B-aligned)
  char* ws = (char*)d_ws;
  ushort* xlr_b = (ushort*)ws; ws += (size_t)MP * 1024 * 2;   // fp16 GAT input
  ushort* hb    = (ushort*)ws; ws += (size_t)MP * 256 * 2;
  ushort* outt  = (ushort*)ws; ws += (size_t)MP * 512 * 2;   // gat concat out
  float*  tmp   = (float*)outt;                               // alias: pre-LN f32 buf
  ushort* hbuf  = (ushort*)outt;                              // alias: head0 out
  ushort* W0t      = (ushort*)ws; ws += (size_t)256 * 1024 * 2;
  ushort* W1t      = (ushort*)ws; ws += (size_t)256 * 256 * 2;
  ushort* WcatT    = (ushort*)ws; ws += (size_t)LAYERS * 1024 * 256 * 2;
  ushort* projcatT = (ushort*)ws; ws += (size_t)LAYERS * 256 * 512 * 2;
  ushort* hW0t     = (ushort*)ws; ws += (size_t)256 * 256 * 2;
  ushort* hW1t     = (ushort*)ws; ws += (size_t)128 * 256 * 2;
  int* cnt0  = (int*)ws; ws += (size_t)NPAD * 4;
  int* cnt1  = (int*)ws; ws += (size_t)NPAD * 4;
  int* offs0 = (int*)ws; ws += (size_t)(N_NODES + 4) * 4;
  int* offs1 = (int*)ws; ws += (size_t)(N_NODES + 4) * 4;
  int* cur0  = (int*)ws; ws += (size_t)N_NODES * 4;
  int* cur1  = (int*)ws; ws += (size_t)N_NODES * 4;
  int* bsums = (int*)ws; ws += (size_t)128 * 4;
  int* boffs = (int*)ws; ws += (size_t)128 * 4;
  int* csr0  = (int*)ws; ws += (size_t)EPRIME * 4;
  int* csr1  = (int*)ws; ws += (size_t)EPRIME * 4;

  // ---- CSR build (deterministic via per-bucket sort)
  hipMemsetAsync(cnt0, 0, (size_t)2 * NPAD * 4, stream);   // cnt0+cnt1 contiguous
  const int gE2 = (2 * EPRIME + 255) / 256;
  csr_count2<<<gE2, 256, 0, stream>>>(ei0, ei1, cnt0, cnt1);
  scan_p1<<<2 * SCAN_NBLK, 256, 0, stream>>>(cnt0, cnt1, bsums);
  scan_p2<<<1, 64, 0, stream>>>(bsums, boffs, offs0, offs1);
  scan_p3<<<2 * SCAN_NBLK, 256, 0, stream>>>(cnt0, cnt1, boffs, offs0, cur0, offs1, cur1);
  csr_scatter2<<<gE2, 256, 0, stream>>>(ei0, ei1, cur0, cur1, csr0, csr1);
  csr_sort2<<<(2 * N_NODES + 255) / 256, 256, 0, stream>>>(offs0, csr0, offs1, csr1);

  // ---- weights -> bf16 K-major (single launch)
  wtrans_all<<<WSEG5 / 256, 256, 0, stream>>>(pre_W0, pre_W1, gat_Wl, gat_Wr, proj_W,
                                              head_W0, head_W1,
                                              W0t, W1t, WcatT, projcatT, hW0t, hW1t);

  const dim3 blk(256);
  const int gy = MP / 128;   // 391
  const int gln = (N_NODES * 64 + 255) / 256;   // 12500

  // ---- preprocessor MLP (pre0 reads f32 x directly, casts in staging)
  gemm_k<true><<<dim3(4, gy), blk, 0, stream>>>(x, W0t, 1024, N_NODES, 256,
                                                tmp, nullptr, pre_b0, nullptr, 0, 0);
  ln_relu<<<gln, 256, 0, stream>>>(tmp, hb, pre_g0, pre_be0, N_NODES);
  gemm_k<false><<<dim3(4, gy), blk, 0, stream>>>(hb, W1t, 256, N_NODES, 256,
                                                 tmp, nullptr, pre_b1, nullptr, 0, 0);
  ln_relu<<<gln, 256, 0, stream>>>(tmp, hb, pre_g1, pre_be1, N_NODES);

  // ---- GNN layers
  for (int l = 0; l < LAYERS; l++) {
    gemm_k<false><<<dim3(16, gy), blk, 0, stream>>>(hb, WcatT + (size_t)l * 1024 * 256,
                                                    256, N_NODES, 1024,
                                                    nullptr, xlr_b, nullptr, nullptr, 0, 1);
    gat_edge3<<<2 * gln, 256, 0, stream>>>(
        (const _Float16*)xlr_b, offs0, csr0, offs1, csr1,
        gat_att  + (size_t)l * NTYPES * NHEAD * DHEAD,
        gat_bias + (size_t)l * NTYPES * HID,
        outt, gln);
    gemm_k<false><<<dim3(4, gy), blk, 0, stream>>>(
        outt, projcatT + (size_t)l * 256 * 512, 512, N_NODES, 256,
        nullptr, hb,
        proj_b + (size_t)(l * NTYPES + 0) * HID,
        proj_b + (size_t)(l * NTYPES + 1) * HID, 1, 0);
  }

  // ---- prediction head
  gemm_k<false><<<dim3(4, gy), blk, 0, stream>>>(hb, hW0t, 256, N_NODES, 256,
                                                 nullptr, hbuf, head_b0, nullptr, 1, 0);
  gemm_k<false><<<dim3(1, gy), blk, 0, stream>>>(hbuf, hW1t, 256, N_NODES, OUT_DIM,
                                                 outp, nullptr, head_b1, nullptr, 0, 0);
}